// Round 16
// baseline (2538.286 us; speedup 1.0000x reference)
//
#include <hip/hip_runtime.h>
#include <cmath>
#include <cstddef>

#define NROWS 8192
#define HDIM  256
#define KNN   11
#define NT    64
#define NTILES (NT*(NT+1)/2)
#define CSTR  (NT*KNN)     // 704 candidates per row

enum { EPI_NONE=0, EPI_RELU=1, EPI_TANH=3, EPI_GATE=4, EPI_SDE=5 };
enum { NPE_NONE=0, NPE_RELU=1, NPE_RELU_BN=2 };

// ---- contraction-proof single-rounding f32 ops (np ufunc semantics) ----
__device__ __forceinline__ float add_rn(float a, float b){ float d; asm("v_add_f32 %0, %1, %2":"=v"(d):"v"(a),"v"(b)); return d; }
__device__ __forceinline__ float sub_rn(float a, float b){ float d; asm("v_sub_f32 %0, %1, %2":"=v"(d):"v"(a),"v"(b)); return d; }
__device__ __forceinline__ float mul_rn(float a, float b){ float d; asm("v_mul_f32 %0, %1, %2":"=v"(d):"v"(a),"v"(b)); return d; }

__device__ __forceinline__ float epi_apply(int EPI, float z, int gn,
    const float* bias, const float* bn_m, const float* bn_r,
    const float* bn_g, const float* bn_b)
{
    if (EPI == NPE_NONE) return z;
    z = add_rn(z, bias[gn]);
    z = fmaxf(z, 0.f);
    if (EPI == NPE_RELU) return z;
    z = sub_rn(z, bn_m[gn]);
    z = mul_rn(z, bn_r[gn]);
    z = mul_rn(z, bn_g[gn]);
    z = add_rn(z, bn_b[gn]);
    return z;
}

// ---- full-comparator guarded sorted-insert: total order (v desc, idx asc).
// Scan-order independent -> any traversal yields THE top-11 under this order.
__device__ __forceinline__ void ins11f(float (&av)[KNN], int (&ai)[KNN], float v, int vi)
{
    if (v > av[KNN - 1] || (v == av[KNN - 1] && vi < ai[KNN - 1])) {
        #pragma unroll
        for (int j = 0; j < KNN; ++j) {
            bool better = (v > av[j]) || (v == av[j] && vi < ai[j]);
            float tv = better ? av[j] : v;  int ti = better ? ai[j] : vi;
            av[j] = better ? v : av[j];     ai[j] = better ? vi : ai[j];
            v = tv; vi = ti;
        }
    }
}

// ======== MULADD-chain GEMM: 128x128 tile, 8x8/thread (proven; encoder) ========
template<int EPI, bool TRANSB>
__global__ __launch_bounds__(256)
void gemm_ma2(const float* __restrict__ A, int lda,
              const float* __restrict__ B, int ldb,
              const float* __restrict__ bias,
              float* __restrict__ C, int ldc,
              int M, int N, int K,
              const float* __restrict__ bn_m, const float* __restrict__ bn_r,
              const float* __restrict__ bn_g, const float* __restrict__ bn_b)
{
    __shared__ float As[32][132];
    __shared__ float Bs[32][132];
    const int tid = threadIdx.x;
    const int tx = tid & 15, ty = tid >> 4;
    const int m0 = blockIdx.y * 128, n0 = blockIdx.x * 128;

    float acc[8][8];
    #pragma unroll
    for (int i = 0; i < 8; ++i)
        #pragma unroll
        for (int j = 0; j < 8; ++j) acc[i][j] = 0.f;

    for (int kc = 0; kc < K; kc += 32) {
        #pragma unroll
        for (int u = 0; u < 16; ++u) {
            int idx = tid + u * 256;
            int kk = idx & 31, m = idx >> 5;
            int gm = m0 + m, gk = kc + kk;
            As[kk][m] = (gm < M && gk < K) ? A[(size_t)gm * lda + gk] : 0.f;
        }
        #pragma unroll
        for (int u = 0; u < 16; ++u) {
            int idx = tid + u * 256;
            if (TRANSB) {
                int kk = idx & 31, n = idx >> 5;
                int gn = n0 + n, gk = kc + kk;
                Bs[kk][n] = (gn < N && gk < K) ? B[(size_t)gn * ldb + gk] : 0.f;
            } else {
                int n = idx & 127, kk = idx >> 7;
                int gn = n0 + n, gk = kc + kk;
                Bs[kk][n] = (gk < K && gn < N) ? B[(size_t)gk * ldb + gn] : 0.f;
            }
        }
        __syncthreads();
        #pragma unroll
        for (int kk = 0; kk < 32; ++kk) {
            float4 a0 = *(const float4*)&As[kk][ty * 8];
            float4 a1 = *(const float4*)&As[kk][ty * 8 + 4];
            float4 b0 = *(const float4*)&Bs[kk][tx * 8];
            float4 b1 = *(const float4*)&Bs[kk][tx * 8 + 4];
            float a[8] = {a0.x,a0.y,a0.z,a0.w,a1.x,a1.y,a1.z,a1.w};
            float b[8] = {b0.x,b0.y,b0.z,b0.w,b1.x,b1.y,b1.z,b1.w};
            #pragma unroll
            for (int i = 0; i < 8; ++i)
                #pragma unroll
                for (int j = 0; j < 8; ++j)
                    acc[i][j] = add_rn(acc[i][j], mul_rn(a[i], b[j]));
        }
        __syncthreads();
    }

    #pragma unroll
    for (int i = 0; i < 8; ++i) {
        int gm = m0 + ty * 8 + i;
        if (gm >= M) continue;
        #pragma unroll
        for (int j = 0; j < 8; ++j) {
            int gn = n0 + tx * 8 + j;
            if (gn >= N) continue;
            C[(size_t)gm * ldc + gn] = epi_apply(EPI, acc[i][j], gn, bias, bn_m, bn_r, bn_g, bn_b);
        }
    }
}

// ======== FUSED sym sim GEMM + per-tile top-11 (both directions) ========
// Upper-triangle tiles only (2080 blocks). Mirror values are bit-identical
// (mul commutes, same ascending-k MULADD chain). After GEMM, tile goes to LDS
// col-major [c][rloc] stride 66 (2-way banks on both scans) in two 64-row
// halves; wave0/1 scan rows (band bc candidates for rows of band br),
// waves2-3 scan cols (band br candidates for rows of band bc; skip if diag).
// Every (row,band) slot written exactly once. Selection = total-order top-11
// => identical to the proven sequential scan.
__global__ __launch_bounds__(256)
void gemm_sim_topk(const float* __restrict__ hn,
                   float* __restrict__ cv, int* __restrict__ ci)
{
    size_t t = blockIdx.x;
    int br = 0;
    while ((size_t)(br + 1) * NT - (size_t)(br + 1) * br / 2 <= t) ++br;
    int bc = br + (int)(t - ((size_t)br * NT - (size_t)br * (br - 1) / 2));

    __shared__ float S[8448];            // staging 2x32x132; reused as T[128][66]
    float* As = S;
    float* Bs = S + 4224;
    const int tid = threadIdx.x;
    const int tx = tid & 15, ty = tid >> 4;
    const int m0 = br * 128, n0 = bc * 128;
    const bool diag = (br == bc);

    float acc[8][8];
    #pragma unroll
    for (int i = 0; i < 8; ++i)
        #pragma unroll
        for (int j = 0; j < 8; ++j) acc[i][j] = 0.f;

    #pragma unroll 1
    for (int kc = 0; kc < HDIM; kc += 32) {
        #pragma unroll
        for (int u = 0; u < 16; ++u) {
            int idx = tid + u * 256;
            int kk = idx & 31, m = idx >> 5;
            As[kk * 132 + m] = hn[(size_t)(m0 + m) * HDIM + kc + kk];
            Bs[kk * 132 + m] = hn[(size_t)(n0 + m) * HDIM + kc + kk];
        }
        __syncthreads();
        #pragma unroll
        for (int kk = 0; kk < 32; ++kk) {
            float4 a0 = *(const float4*)&As[kk * 132 + ty * 8];
            float4 a1 = *(const float4*)&As[kk * 132 + ty * 8 + 4];
            float4 b0 = *(const float4*)&Bs[kk * 132 + tx * 8];
            float4 b1 = *(const float4*)&Bs[kk * 132 + tx * 8 + 4];
            float a[8] = {a0.x,a0.y,a0.z,a0.w,a1.x,a1.y,a1.z,a1.w};
            float b[8] = {b0.x,b0.y,b0.z,b0.w,b1.x,b1.y,b1.z,b1.w};
            #pragma unroll
            for (int i = 0; i < 8; ++i)
                #pragma unroll
                for (int j = 0; j < 8; ++j)
                    acc[i][j] = add_rn(acc[i][j], mul_rn(a[i], b[j]));
        }
        __syncthreads();
    }

    float* T = S;                        // T[c*66 + rloc], rloc in [0,64)
    // col-scan state (waves 2-3): column c = tid-128
    float cav[KNN]; int cai[KNN];
    #pragma unroll
    for (int j = 0; j < KNN; ++j) { cav[j] = -3.402823e38f; cai[j] = 0x7fffffff; }

    // ---- half 0: tile rows 0..63 (held by threads ty<8) ----
    if (ty < 8) {
        #pragma unroll
        for (int i = 0; i < 8; ++i) {
            int rloc = ty * 8 + i;
            #pragma unroll
            for (int j = 0; j < 8; ++j)
                T[(tx * 8 + j) * 66 + rloc] = acc[i][j];
        }
    }
    __syncthreads();
    if (tid < 64) {
        // wave0: row scan, rows m0+0..63, candidates = this tile's 128 cols
        float av[KNN]; int ai[KNN];
        #pragma unroll
        for (int j = 0; j < KNN; ++j) { av[j] = -3.402823e38f; ai[j] = 0x7fffffff; }
        #pragma unroll 4
        for (int c = 0; c < 128; ++c)
            ins11f(av, ai, T[c * 66 + tid], n0 + c);
        int row = m0 + tid;
        #pragma unroll
        for (int j = 0; j < KNN; ++j) {
            cv[(size_t)row * CSTR + bc * KNN + j] = av[j];
            ci[(size_t)row * CSTR + bc * KNN + j] = ai[j];
        }
    } else if (tid >= 128 && !diag) {
        int c = tid - 128;
        #pragma unroll 4
        for (int rl = 0; rl < 64; rl += 2) {
            float2 v2 = *(const float2*)&T[c * 66 + rl];
            ins11f(cav, cai, v2.x, m0 + rl);
            ins11f(cav, cai, v2.y, m0 + rl + 1);
        }
    }
    __syncthreads();

    // ---- half 1: tile rows 64..127 (held by threads ty>=8) ----
    if (ty >= 8) {
        #pragma unroll
        for (int i = 0; i < 8; ++i) {
            int rloc = ty * 8 + i - 64;
            #pragma unroll
            for (int j = 0; j < 8; ++j)
                T[(tx * 8 + j) * 66 + rloc] = acc[i][j];
        }
    }
    __syncthreads();
    if (tid >= 64 && tid < 128) {
        // wave1: row scan, rows m0+64..127
        int rloc = tid - 64;
        float av[KNN]; int ai[KNN];
        #pragma unroll
        for (int j = 0; j < KNN; ++j) { av[j] = -3.402823e38f; ai[j] = 0x7fffffff; }
        #pragma unroll 4
        for (int c = 0; c < 128; ++c)
            ins11f(av, ai, T[c * 66 + rloc], n0 + c);
        int row = m0 + 64 + rloc;
        #pragma unroll
        for (int j = 0; j < KNN; ++j) {
            cv[(size_t)row * CSTR + bc * KNN + j] = av[j];
            ci[(size_t)row * CSTR + bc * KNN + j] = ai[j];
        }
    } else if (tid >= 128 && !diag) {
        int c = tid - 128;
        #pragma unroll 4
        for (int rl = 0; rl < 64; rl += 2) {
            float2 v2 = *(const float2*)&T[c * 66 + rl];
            ins11f(cav, cai, v2.x, m0 + 64 + rl);
            ins11f(cav, cai, v2.y, m0 + 64 + rl + 1);
        }
        // mirror candidates: row n0+c, band br
        int row = n0 + c;
        #pragma unroll
        for (int j = 0; j < KNN; ++j) {
            cv[(size_t)row * CSTR + br * KNN + j] = cav[j];
            ci[(size_t)row * CSTR + br * KNN + j] = cai[j];
        }
    }
}

// ======== merge per-band top-11 lists -> global top-11 per row ========
__global__ __launch_bounds__(256)
void topk_merge(const float* __restrict__ cv, const int* __restrict__ ci,
                int* __restrict__ idx_out, float* __restrict__ wgt_out)
{
    const int wid = blockIdx.x * 4 + (threadIdx.x >> 6);   // row
    const int lane = threadIdx.x & 63;                     // band

    const float* v = cv + (size_t)wid * CSTR + lane * KNN;
    const int*   x = ci + (size_t)wid * CSTR + lane * KNN;
    float av[KNN]; int ai[KNN];
    #pragma unroll
    for (int j = 0; j < KNN; ++j) { av[j] = v[j]; ai[j] = x[j]; }

    #pragma unroll 1
    for (int m = 1; m < 64; m <<= 1) {
        float bv[KNN]; int bi[KNN];
        #pragma unroll
        for (int j = 0; j < KNN; ++j) {
            bv[j] = __shfl_xor(av[j], m, 64);
            bi[j] = __shfl_xor(ai[j], m, 64);
        }
        #pragma unroll
        for (int j = 0; j < KNN; ++j)
            ins11f(av, ai, bv[j], bi[j]);
    }

    if (lane == 0) {
        double s = 0.0;
        #pragma unroll
        for (int j = 0; j < KNN; ++j) s += (double)av[j];
        double den = fmax(s, 1.0);
        #pragma unroll
        for (int j = 0; j < KNN; ++j) {
            idx_out[(size_t)wid * KNN + j] = ai[j];
            wgt_out[(size_t)wid * KNN + j] = (float)((double)av[j] / den);
        }
    }
}

// ---- BN reciprocal-sqrt ----
__global__ void bn_prep_np(const float* __restrict__ v, float* __restrict__ r)
{
    int i = threadIdx.x;
    float vpe = add_rn(v[i], 1e-5f);
    r[i] = 1.0f / sqrtf(vpe);
}

// ---- numpy scalar-pairwise row L2-normalize ----
__global__ __launch_bounds__(256)
void rownorm_np2(const float* __restrict__ h, float* __restrict__ hn)
{
    int r = blockIdx.x * 256 + threadIdx.x;
    if (r >= NROWS) return;
    const float* x = h + (size_t)r * HDIM;
    float tot = 0.f;
    #pragma unroll
    for (int half = 0; half < 2; ++half) {
        const float* a = x + half * 128;
        float rr[8];
        #pragma unroll
        for (int jj = 0; jj < 8; ++jj) rr[jj] = mul_rn(a[jj], a[jj]);
        #pragma unroll 1
        for (int ii = 8; ii < 128; ii += 8) {
            #pragma unroll
            for (int jj = 0; jj < 8; ++jj) rr[jj] = add_rn(rr[jj], mul_rn(a[ii + jj], a[ii + jj]));
        }
        float blk = add_rn(add_rn(add_rn(rr[0], rr[1]), add_rn(rr[2], rr[3])),
                           add_rn(add_rn(rr[4], rr[5]), add_rn(rr[6], rr[7])));
        tot = (half == 0) ? blk : add_rn(tot, blk);
    }
    float den = fmaxf(sqrtf(tot), 1e-12f);
    float* o = hn + (size_t)r * HDIM;
    for (int ii = 0; ii < HDIM; ++ii) o[ii] = x[ii] / den;
}

// ================= fused SDE (proven) =================
#define SROWS 16
#define SSTR  (HDIM + 4)

__device__ __forceinline__ void sde_layer(
    const float (*in)[SSTR], float (*out)[SSTR],
    const float* __restrict__ W, const float* __restrict__ bias,
    const float* __restrict__ tw, float t, int rg, int cg)
{
    __syncthreads();
    float acc[4][4];
    #pragma unroll
    for (int i = 0; i < 4; ++i)
        #pragma unroll
        for (int j = 0; j < 4; ++j) acc[i][j] = 0.f;

    #pragma unroll 1
    for (int k = 0; k < HDIM; k += 4) {
        float4 a4[4];
        #pragma unroll
        for (int i = 0; i < 4; ++i) a4[i] = *(const float4*)&in[rg * 4 + i][k];
        float4 w4[4];
        #pragma unroll
        for (int q = 0; q < 4; ++q) w4[q] = *(const float4*)&W[(size_t)(k + q) * HDIM + cg * 4];
        #pragma unroll
        for (int i = 0; i < 4; ++i) {
            float avv[4] = {a4[i].x, a4[i].y, a4[i].z, a4[i].w};
            #pragma unroll
            for (int q = 0; q < 4; ++q) {
                acc[i][0] = __builtin_fmaf(avv[q], w4[q].x, acc[i][0]);
                acc[i][1] = __builtin_fmaf(avv[q], w4[q].y, acc[i][1]);
                acc[i][2] = __builtin_fmaf(avv[q], w4[q].z, acc[i][2]);
                acc[i][3] = __builtin_fmaf(avv[q], w4[q].w, acc[i][3]);
            }
        }
    }

    float bb[4];
    #pragma unroll
    for (int j = 0; j < 4; ++j) {
        bb[j] = bias[cg * 4 + j];
        if (tw) bb[j] += t * tw[cg * 4 + j];
    }
    #pragma unroll
    for (int i = 0; i < 4; ++i)
        #pragma unroll
        for (int j = 0; j < 4; ++j)
            out[rg * 4 + i][cg * 4 + j] = tanhf(acc[i][j] + bb[j]);
}

__global__ __launch_bounds__(256)
void sde_fused(const float* __restrict__ w1, const float* __restrict__ b1,
               const float* __restrict__ w2, const float* __restrict__ b2,
               const float* __restrict__ w3, const float* __restrict__ b3,
               float* __restrict__ h)
{
    __shared__ float hs[SROWS][SSTR];
    __shared__ float bufA[SROWS][SSTR];
    __shared__ float bufB[SROWS][SSTR];
    const int tid = threadIdx.x;
    const int r0 = blockIdx.x * SROWS;
    const int rg = tid >> 6;
    const int cg = tid & 63;

    for (int i = tid; i < SROWS * HDIM; i += 256) {
        int r = i >> 8, c = i & 255;
        hs[r][c] = h[(size_t)(r0 + r) * HDIM + c];
    }

    #pragma unroll 1
    for (int s = 0; s < 10; ++s) {
        float t = 0.1f * (float)s;
        sde_layer(hs,  bufA, w1, b1, w1 + (size_t)HDIM * HDIM, t, rg, cg);
        sde_layer(bufA, bufB, w2, b2, nullptr, 0.f, rg, cg);
        sde_layer(bufB, bufA, w3, b3, nullptr, 0.f, rg, cg);
        __syncthreads();
        for (int i = tid; i < SROWS * HDIM; i += 256) {
            int r = i >> 8, c = i & 255;
            hs[r][c] += 0.1f * bufA[r][c];
        }
    }
    __syncthreads();
    for (int i = tid; i < SROWS * HDIM; i += 256) {
        int r = i >> 8, c = i & 255;
        h[(size_t)(r0 + r) * HDIM + c] = hs[r][c];
    }
}

// ================= downstream 64-tile GEMM (proven) =================
template<int EPI, bool TRANSB>
__global__ __launch_bounds__(256)
void gemm_f32(const float* __restrict__ A, int lda,
              const float* __restrict__ B, int ldb,
              const float* __restrict__ bias, const float* __restrict__ bias2, float bcoef,
              float* __restrict__ C, int ldc,
              int M, int N, int K,
              const float* __restrict__ E1, const float* __restrict__ E2, float coef)
{
    __shared__ float As[16][64];
    __shared__ float Bs[16][64];
    const int tid = threadIdx.x;
    const int tx = tid & 15, ty = tid >> 4;
    const int m0 = blockIdx.y * 64, n0 = blockIdx.x * 64;

    float acc[4][4] = {{0.f}};

    for (int k0 = 0; k0 < K; k0 += 16) {
        #pragma unroll
        for (int u = 0; u < 4; ++u) {
            int i = tid + u * 256;
            int kk = i & 15, m = i >> 4;
            int gm = m0 + m, gk = k0 + kk;
            As[kk][m] = (gm < M && gk < K) ? A[(size_t)gm * lda + gk] : 0.f;
        }
        if (!TRANSB) {
            #pragma unroll
            for (int u = 0; u < 4; ++u) {
                int i = tid + u * 256;
                int n = i & 63, kk = i >> 6;
                int gk = k0 + kk, gn = n0 + n;
                Bs[kk][n] = (gk < K && gn < N) ? B[(size_t)gk * ldb + gn] : 0.f;
            }
        } else {
            #pragma unroll
            for (int u = 0; u < 4; ++u) {
                int i = tid + u * 256;
                int kk = i & 15, n = i >> 4;
                int gk = k0 + kk, gn = n0 + n;
                Bs[kk][n] = (gk < K && gn < N) ? B[(size_t)gn * ldb + gk] : 0.f;
            }
        }
        __syncthreads();
        #pragma unroll
        for (int kk = 0; kk < 16; ++kk) {
            float4 avv = *(const float4*)&As[kk][ty * 4];
            float4 bvv = *(const float4*)&Bs[kk][tx * 4];
            float a[4] = {avv.x, avv.y, avv.z, avv.w};
            float b[4] = {bvv.x, bvv.y, bvv.z, bvv.w};
            #pragma unroll
            for (int i2 = 0; i2 < 4; ++i2)
                #pragma unroll
                for (int j = 0; j < 4; ++j)
                    acc[i2][j] += a[i2] * b[j];
        }
        __syncthreads();
    }

    #pragma unroll
    for (int i2 = 0; i2 < 4; ++i2) {
        int gm = m0 + ty * 4 + i2;
        if (gm >= M) continue;
        #pragma unroll
        for (int j = 0; j < 4; ++j) {
            int gn = n0 + tx * 4 + j;
            if (gn >= N) continue;
            float z = acc[i2][j];
            if (bias)  z += bias[gn];
            if (bias2) z += bcoef * bias2[gn];
            float r;
            if constexpr (EPI == EPI_NONE) {
                r = z;
            } else if constexpr (EPI == EPI_RELU) {
                r = fmaxf(z, 0.f);
            } else if constexpr (EPI == EPI_TANH) {
                r = tanhf(z);
            } else if constexpr (EPI == EPI_GATE) {
                float g = 1.f / (1.f + expf(-z));
                float avv = E1[(size_t)gm * ldc + gn];
                float hvv = E2[(size_t)gm * ldc + gn];
                r = fmaxf(g * avv + (1.f - g) * hvv, 0.f);
            } else {
                r = E1[(size_t)gm * ldc + gn] + tanhf(z) * coef;
            }
            C[(size_t)gm * ldc + gn] = r;
        }
    }
}

__global__ __launch_bounds__(256)
void gather_agg(const float* __restrict__ ht, const int* __restrict__ idx,
                const float* __restrict__ wgt, float* __restrict__ agg)
{
    int r = blockIdx.x, tid = threadIdx.x;
    __shared__ int   si[KNN];
    __shared__ float sw[KNN];
    if (tid < KNN) { si[tid] = idx[(size_t)r * KNN + tid]; sw[tid] = wgt[(size_t)r * KNN + tid]; }
    __syncthreads();
    float acc = 0.f;
    #pragma unroll
    for (int j = 0; j < KNN; ++j) acc += sw[j] * ht[(size_t)si[j] * HDIM + tid];
    agg[(size_t)r * HDIM + tid] = acc;
}

__global__ __launch_bounds__(256)
void te_gbias(const float* __restrict__ w1, const float* __restrict__ b1,
              const float* __restrict__ w2, const float* __restrict__ b2,
              const float* __restrict__ gw, const float* __restrict__ gb,
              float t, float* __restrict__ gbias)
{
    __shared__ float hid[16];
    __shared__ float te[256];
    int tid = threadIdx.x;
    if (tid < 16) hid[tid] = fmaxf(t * w1[tid] + b1[tid], 0.f);
    __syncthreads();
    float acc = b2[tid];
    #pragma unroll
    for (int i = 0; i < 16; ++i) acc += hid[i] * w2[i * 256 + tid];
    te[tid] = acc;
    __syncthreads();
    float g = gb[tid];
    for (int j = 0; j < 256; ++j) g += te[j] * gw[j * 256 + tid];
    gbias[tid] = g;
}

extern "C" void kernel_launch(void* const* d_in, const int* in_sizes, int n_in,
                              void* d_out, int out_size, void* d_ws, size_t ws_size,
                              hipStream_t stream)
{
    (void)in_sizes; (void)n_in; (void)out_size; (void)ws_size;
    const float* x       = (const float*)d_in[0];
    const float* enc_w1  = (const float*)d_in[1];
    const float* enc_b1  = (const float*)d_in[2];
    const float* enc_w2  = (const float*)d_in[3];
    const float* enc_b2  = (const float*)d_in[4];
    const float* bn_g    = (const float*)d_in[5];
    const float* bn_b    = (const float*)d_in[6];
    const float* bn_m    = (const float*)d_in[7];
    const float* bn_v    = (const float*)d_in[8];
    const float* tg_node_w = (const float*)d_in[9];
    const float* tg_node_b = (const float*)d_in[10];
    const float* tg_t_w1 = (const float*)d_in[11];
    const float* tg_t_b1 = (const float*)d_in[12];
    const float* tg_t_w2 = (const float*)d_in[13];
    const float* tg_t_b2 = (const float*)d_in[14];
    const float* tg_gate_w = (const float*)d_in[15];
    const float* tg_gate_b = (const float*)d_in[16];
    const float* sde_w1  = (const float*)d_in[17];
    const float* sde_b1  = (const float*)d_in[18];
    const float* sde_w2  = (const float*)d_in[19];
    const float* sde_b2  = (const float*)d_in[20];
    const float* sde_w3  = (const float*)d_in[21];
    const float* sde_b3  = (const float*)d_in[22];
    const float* dec_w1  = (const float*)d_in[23];
    const float* dec_b1  = (const float*)d_in[24];
    const float* dec_w2  = (const float*)d_in[25];
    const float* dec_b2  = (const float*)d_in[26];
    float* out = (float*)d_out;

    const size_t NH = (size_t)NROWS * HDIM;
    const size_t NK = (size_t)NROWS * KNN;

    char* p = (char*)d_ws;
    float* h    = (float*)p;  p += NH * 4;
    float* hn   = (float*)p;  p += NH * 4;
    float* t1   = (float*)p;  p += NH * 4;
    float* t2   = (float*)p;  p += NH * 4;
    int*   ki   = (int*)p;    p += NK * 4;
    float* kw   = (float*)p;  p += NK * 4;
    float* bn_r   = (float*)p; p += 256 * 4;
    float* gbias  = (float*)p; p += 256 * 4;
    p += (16 - ((uintptr_t)p & 15)) & 15;
    float* cv = (float*)p;    p += (size_t)NROWS * CSTR * 4;   // 23 MB
    int*   ci = (int*)p;      p += (size_t)NROWS * CSTR * 4;   // 23 MB

    dim3 blk(256);
    dim3 g64(4, NROWS / 64);
    dim3 g128(2, NROWS / 128);

    bn_prep_np<<<1, 256, 0, stream>>>(bn_v, bn_r);

    // ---- np-matching MULADD chain: encoder -> norm -> fused sim+topk -> merge
    gemm_ma2<NPE_RELU, false><<<g128, blk, 0, stream>>>(
        x, 83, enc_w1, 256, enc_b1, t1, 256, NROWS, 256, 83, nullptr, nullptr, nullptr, nullptr);
    gemm_ma2<NPE_RELU_BN, false><<<g128, blk, 0, stream>>>(
        t1, 256, enc_w2, 256, enc_b2, h, 256, NROWS, 256, 256, bn_m, bn_r, bn_g, bn_b);
    rownorm_np2<<<NROWS / 256, 256, 0, stream>>>(h, hn);

    gemm_sim_topk<<<NTILES, blk, 0, stream>>>(hn, cv, ci);
    topk_merge<<<NROWS / 4, 256, 0, stream>>>(cv, ci, ki, kw);

    // ---- temporal gated graph conv layers (proven 64-tile fp32)
    float tval = 0.f;
    for (int l = 0; l < 2; ++l) {
        te_gbias<<<1, 256, 0, stream>>>(
            tg_t_w1 + l * 16, tg_t_b1 + l * 16,
            tg_t_w2 + (size_t)l * 16 * 256, tg_t_b2 + l * 256,
            tg_gate_w + ((size_t)l * 512 + 256) * 256, tg_gate_b + l * 256,
            tval, gbias);
        gemm_f32<EPI_NONE, false><<<g64, blk, 0, stream>>>(
            h, 256, tg_node_w + (size_t)l * 256 * 256, 256,
            tg_node_b + l * 256, nullptr, 0.f, t1, 256, NROWS, 256, 256,
            nullptr, nullptr, 0.f);
        gather_agg<<<NROWS, 256, 0, stream>>>(t1, ki, kw, t2);
        gemm_f32<EPI_GATE, false><<<g64, blk, 0, stream>>>(
            t2, 256, tg_gate_w + (size_t)l * 512 * 256, 256,
            gbias, nullptr, 0.f, h, 256, NROWS, 256, 256,
            t2, t1, 0.f);
        tval += 0.5f;
    }

    // ---- fused SDE
    sde_fused<<<NROWS / SROWS, 256, 0, stream>>>(
        sde_w1, sde_b1, sde_w2, sde_b2, sde_w3, sde_b3, h);

    // ---- decoder
    gemm_f32<EPI_RELU, false><<<dim3(2, NROWS / 64), blk, 0, stream>>>(
        h, 256, dec_w1, 128, dec_b1, nullptr, 0.f, t1, 128, NROWS, 128, 256,
        nullptr, nullptr, 0.f);
    gemm_f32<EPI_NONE, false><<<dim3(1, NROWS / 64), blk, 0, stream>>>(
        t1, 128, dec_w2, 34, dec_b2, nullptr, 0.f, out, 34, NROWS, 34, 128,
        nullptr, nullptr, 0.f);
}

// Round 17
// 2343.033 us; speedup vs baseline: 1.0833x; 1.0833x over previous
//
#include <hip/hip_runtime.h>
#include <cmath>
#include <cstddef>

#define NROWS 8192
#define HDIM  256
#define KNN   11
#define NT    64
#define TS    128
#define TILE_ELEMS (TS*TS)
#define NTILES (NT*(NT+1)/2)
#define CSTR  (NT*KNN)

enum { EPI_NONE=0, EPI_RELU=1, EPI_TANH=3, EPI_GATE=4, EPI_SDE=5 };
enum { NPE_NONE=0, NPE_RELU=1, NPE_RELU_BN=2 };

// ---- contraction-proof single-rounding f32 ops (np ufunc semantics) ----
__device__ __forceinline__ float add_rn(float a, float b){ float d; asm("v_add_f32 %0, %1, %2":"=v"(d):"v"(a),"v"(b)); return d; }
__device__ __forceinline__ float sub_rn(float a, float b){ float d; asm("v_sub_f32 %0, %1, %2":"=v"(d):"v"(a),"v"(b)); return d; }
__device__ __forceinline__ float mul_rn(float a, float b){ float d; asm("v_mul_f32 %0, %1, %2":"=v"(d):"v"(a),"v"(b)); return d; }

__device__ __host__ __forceinline__ size_t tidx(int br, int bc)
{   // row-major upper-triangle packing, br <= bc
    return (size_t)br * NT - (size_t)br * (br - 1) / 2 + (size_t)(bc - br);
}

__device__ __forceinline__ float epi_apply(int EPI, float z, int gn,
    const float* bias, const float* bn_m, const float* bn_r,
    const float* bn_g, const float* bn_b)
{
    if (EPI == NPE_NONE) return z;
    z = add_rn(z, bias[gn]);
    z = fmaxf(z, 0.f);
    if (EPI == NPE_RELU) return z;
    z = sub_rn(z, bn_m[gn]);
    z = mul_rn(z, bn_r[gn]);
    z = mul_rn(z, bn_g[gn]);
    z = add_rn(z, bn_b[gn]);
    return z;
}

// ---- full-comparator guarded sorted-insert: total order (v desc, idx asc).
// Scan-order independent (HW-verified bit-exact in R16).
__device__ __forceinline__ void ins11f(float (&av)[KNN], int (&ai)[KNN], float v, int vi)
{
    if (v > av[KNN - 1] || (v == av[KNN - 1] && vi < ai[KNN - 1])) {
        #pragma unroll
        for (int j = 0; j < KNN; ++j) {
            bool better = (v > av[j]) || (v == av[j] && vi < ai[j]);
            float tv = better ? av[j] : v;  int ti = better ? ai[j] : vi;
            av[j] = better ? v : av[j];     ai[j] = better ? vi : ai[j];
            v = tv; vi = ti;
        }
    }
}

// ======== MULADD-chain GEMM: 128x128 tile, 8x8/thread (proven; encoder) ========
template<int EPI, bool TRANSB>
__global__ __launch_bounds__(256)
void gemm_ma2(const float* __restrict__ A, int lda,
              const float* __restrict__ B, int ldb,
              const float* __restrict__ bias,
              float* __restrict__ C, int ldc,
              int M, int N, int K,
              const float* __restrict__ bn_m, const float* __restrict__ bn_r,
              const float* __restrict__ bn_g, const float* __restrict__ bn_b)
{
    __shared__ float As[32][132];
    __shared__ float Bs[32][132];
    const int tid = threadIdx.x;
    const int tx = tid & 15, ty = tid >> 4;
    const int m0 = blockIdx.y * 128, n0 = blockIdx.x * 128;

    float acc[8][8];
    #pragma unroll
    for (int i = 0; i < 8; ++i)
        #pragma unroll
        for (int j = 0; j < 8; ++j) acc[i][j] = 0.f;

    for (int kc = 0; kc < K; kc += 32) {
        #pragma unroll
        for (int u = 0; u < 16; ++u) {
            int idx = tid + u * 256;
            int kk = idx & 31, m = idx >> 5;
            int gm = m0 + m, gk = kc + kk;
            As[kk][m] = (gm < M && gk < K) ? A[(size_t)gm * lda + gk] : 0.f;
        }
        #pragma unroll
        for (int u = 0; u < 16; ++u) {
            int idx = tid + u * 256;
            if (TRANSB) {
                int kk = idx & 31, n = idx >> 5;
                int gn = n0 + n, gk = kc + kk;
                Bs[kk][n] = (gn < N && gk < K) ? B[(size_t)gn * ldb + gk] : 0.f;
            } else {
                int n = idx & 127, kk = idx >> 7;
                int gn = n0 + n, gk = kc + kk;
                Bs[kk][n] = (gk < K && gn < N) ? B[(size_t)gk * ldb + gn] : 0.f;
            }
        }
        __syncthreads();
        #pragma unroll
        for (int kk = 0; kk < 32; ++kk) {
            float4 a0 = *(const float4*)&As[kk][ty * 8];
            float4 a1 = *(const float4*)&As[kk][ty * 8 + 4];
            float4 b0 = *(const float4*)&Bs[kk][tx * 8];
            float4 b1 = *(const float4*)&Bs[kk][tx * 8 + 4];
            float a[8] = {a0.x,a0.y,a0.z,a0.w,a1.x,a1.y,a1.z,a1.w};
            float b[8] = {b0.x,b0.y,b0.z,b0.w,b1.x,b1.y,b1.z,b1.w};
            #pragma unroll
            for (int i = 0; i < 8; ++i)
                #pragma unroll
                for (int j = 0; j < 8; ++j)
                    acc[i][j] = add_rn(acc[i][j], mul_rn(a[i], b[j]));
        }
        __syncthreads();
    }

    #pragma unroll
    for (int i = 0; i < 8; ++i) {
        int gm = m0 + ty * 8 + i;
        if (gm >= M) continue;
        #pragma unroll
        for (int j = 0; j < 8; ++j) {
            int gn = n0 + tx * 8 + j;
            if (gn >= N) continue;
            C[(size_t)gm * ldc + gn] = epi_apply(EPI, acc[i][j], gn, bias, bn_m, bn_r, bn_g, bn_b);
        }
    }
}

// ======== sym sim GEMM -> PACKED upper tiles; 1D grid (R15, proven) ========
__global__ __launch_bounds__(256)
void gemm_sim_sym_packed(const float* __restrict__ hn, float* __restrict__ P)
{
    size_t t = blockIdx.x;
    int br = 0;
    while ((size_t)(br + 1) * NT - (size_t)(br + 1) * br / 2 <= t) ++br;
    int bc = br + (int)(t - ((size_t)br * NT - (size_t)br * (br - 1) / 2));

    __shared__ float As[32][132];
    __shared__ float Bs[32][132];
    const int tid = threadIdx.x;
    const int tx = tid & 15, ty = tid >> 4;
    const int m0 = br * 128, n0 = bc * 128;

    float acc[8][8];
    #pragma unroll
    for (int i = 0; i < 8; ++i)
        #pragma unroll
        for (int j = 0; j < 8; ++j) acc[i][j] = 0.f;

    #pragma unroll 1
    for (int kc = 0; kc < HDIM; kc += 32) {
        #pragma unroll
        for (int u = 0; u < 16; ++u) {
            int idx = tid + u * 256;
            int kk = idx & 31, m = idx >> 5;
            As[kk][m] = hn[(size_t)(m0 + m) * HDIM + kc + kk];
            Bs[kk][m] = hn[(size_t)(n0 + m) * HDIM + kc + kk];
        }
        __syncthreads();
        #pragma unroll
        for (int kk = 0; kk < 32; ++kk) {
            float4 a0 = *(const float4*)&As[kk][ty * 8];
            float4 a1 = *(const float4*)&As[kk][ty * 8 + 4];
            float4 b0 = *(const float4*)&Bs[kk][tx * 8];
            float4 b1 = *(const float4*)&Bs[kk][tx * 8 + 4];
            float a[8] = {a0.x,a0.y,a0.z,a0.w,a1.x,a1.y,a1.z,a1.w};
            float b[8] = {b0.x,b0.y,b0.z,b0.w,b1.x,b1.y,b1.z,b1.w};
            #pragma unroll
            for (int i = 0; i < 8; ++i)
                #pragma unroll
                for (int j = 0; j < 8; ++j)
                    acc[i][j] = add_rn(acc[i][j], mul_rn(a[i], b[j]));
        }
        __syncthreads();
    }

    float* tile = P + t * TILE_ELEMS;
    #pragma unroll
    for (int i = 0; i < 8; ++i) {
        float* tr = tile + (size_t)(ty * 8 + i) * TS + tx * 8;
        #pragma unroll
        for (int j = 0; j < 8; ++j) tr[j] = acc[i][j];
    }
}

// ======== topk stage 1a: DIRECT bands (cb >= br), wave per row, coalesced ========
// Combined top-11 over all direct columns -> band-slot br.
__global__ __launch_bounds__(256)
void topk_direct(const float* __restrict__ P,
                 float* __restrict__ cv, int* __restrict__ ci)
{
    const int wid = blockIdx.x * 4 + (threadIdx.x >> 6);
    const int lane = threadIdx.x & 63;
    const int br = wid >> 7, rr = wid & 127;

    float av[KNN]; int ai[KNN];
    #pragma unroll
    for (int j = 0; j < KNN; ++j) { av[j] = -3.402823e38f; ai[j] = 0x7fffffff; }

    #pragma unroll 1
    for (int cb = br; cb < NT; ++cb) {
        const float* tile = P + tidx(br, cb) * TILE_ELEMS;
        float2 v2 = *(const float2*)&tile[(size_t)rr * TS + lane * 2];
        int c0 = cb * TS + lane * 2;
        ins11f(av, ai, v2.x, c0);
        ins11f(av, ai, v2.y, c0 + 1);
    }

    #pragma unroll 1
    for (int m = 1; m < 64; m <<= 1) {
        float bv[KNN]; int bi[KNN];
        #pragma unroll
        for (int j = 0; j < KNN; ++j) {
            bv[j] = __shfl_xor(av[j], m, 64);
            bi[j] = __shfl_xor(ai[j], m, 64);
        }
        #pragma unroll
        for (int j = 0; j < KNN; ++j)
            ins11f(av, ai, bv[j], bi[j]);
    }

    if (lane == 0) {
        #pragma unroll
        for (int j = 0; j < KNN; ++j) {
            cv[(size_t)wid * CSTR + br * KNN + j] = av[j];
            ci[(size_t)wid * CSTR + br * KNN + j] = ai[j];
        }
    }
}

// ======== topk stage 1b: MIRROR bands — block per off-diag tile (a,b), a<b ========
// tile(a,b) columns = rows of band b; per-column top-11 -> slot a.
// Two 64-row transposed LDS halves; coalesced global reads; 2-way LDS.
__global__ __launch_bounds__(256)
void topk_mirror(const float* __restrict__ P,
                 float* __restrict__ cv, int* __restrict__ ci)
{
    size_t t = blockIdx.x;
    int a = 0;
    while ((size_t)(a + 1) * NT - (size_t)(a + 1) * a / 2 <= t) ++a;
    int b = a + (int)(t - ((size_t)a * NT - (size_t)a * (a - 1) / 2));
    if (a == b) return;

    __shared__ float TT[TS][66];     // [col][rowLocal 0..63]
    const int tid = threadIdx.x;
    const float* tile = P + t * TILE_ELEMS;

    float av[KNN]; int ai[KNN];
    #pragma unroll
    for (int j = 0; j < KNN; ++j) { av[j] = -3.402823e38f; ai[j] = 0x7fffffff; }
    const int c = tid & 127;         // column owned by threads 0..127

    #pragma unroll 1
    for (int half = 0; half < 2; ++half) {
        int rstart = half * 64;
        __syncthreads();
        {   // stage: thread loads 8 float4 of row r, cols cq*32..+31 (coalesced)
            int r = rstart + (tid >> 2), cq = tid & 3;
            const float* rowp = tile + (size_t)r * TS + cq * 32;
            #pragma unroll
            for (int q = 0; q < 8; ++q) {
                float4 v4 = *(const float4*)&rowp[q * 4];
                int cc = cq * 32 + q * 4;
                TT[cc + 0][r - rstart] = v4.x;
                TT[cc + 1][r - rstart] = v4.y;
                TT[cc + 2][r - rstart] = v4.z;
                TT[cc + 3][r - rstart] = v4.w;
            }
        }
        __syncthreads();
        if (tid < 128) {
            #pragma unroll 4
            for (int rl = 0; rl < 64; ++rl)
                ins11f(av, ai, TT[c][rl], a * TS + rstart + rl);
        }
    }

    if (tid < 128) {
        int row = b * TS + c;
        #pragma unroll
        for (int j = 0; j < KNN; ++j) {
            cv[(size_t)row * CSTR + a * KNN + j] = av[j];
            ci[(size_t)row * CSTR + a * KNN + j] = ai[j];
        }
    }
}

// ======== topk stage 2: merge band lists (valid slots: 0..br) ========
__global__ __launch_bounds__(256)
void topk_merge_b(const float* __restrict__ cv, const int* __restrict__ ci,
                  int* __restrict__ idx_out, float* __restrict__ wgt_out)
{
    const int wid = blockIdx.x * 4 + (threadIdx.x >> 6);
    const int lane = threadIdx.x & 63;
    const int br = wid >> 7;

    float av[KNN]; int ai[KNN];
    if (lane <= br) {
        const float* v = cv + (size_t)wid * CSTR + lane * KNN;
        const int*   x = ci + (size_t)wid * CSTR + lane * KNN;
        #pragma unroll
        for (int j = 0; j < KNN; ++j) { av[j] = v[j]; ai[j] = x[j]; }
    } else {
        #pragma unroll
        for (int j = 0; j < KNN; ++j) { av[j] = -3.402823e38f; ai[j] = 0x7fffffff; }
    }

    #pragma unroll 1
    for (int m = 1; m < 64; m <<= 1) {
        float bv[KNN]; int bi[KNN];
        #pragma unroll
        for (int j = 0; j < KNN; ++j) {
            bv[j] = __shfl_xor(av[j], m, 64);
            bi[j] = __shfl_xor(ai[j], m, 64);
        }
        #pragma unroll
        for (int j = 0; j < KNN; ++j)
            ins11f(av, ai, bv[j], bi[j]);
    }

    if (lane == 0) {
        double s = 0.0;
        #pragma unroll
        for (int j = 0; j < KNN; ++j) s += (double)av[j];
        double den = fmax(s, 1.0);
        #pragma unroll
        for (int j = 0; j < KNN; ++j) {
            idx_out[(size_t)wid * KNN + j] = ai[j];
            wgt_out[(size_t)wid * KNN + j] = (float)((double)av[j] / den);
        }
    }
}

// ---- BN reciprocal-sqrt ----
__global__ void bn_prep_np(const float* __restrict__ v, float* __restrict__ r)
{
    int i = threadIdx.x;
    float vpe = add_rn(v[i], 1e-5f);
    r[i] = 1.0f / sqrtf(vpe);
}

// ---- numpy scalar-pairwise row L2-normalize ----
__global__ __launch_bounds__(256)
void rownorm_np2(const float* __restrict__ h, float* __restrict__ hn)
{
    int r = blockIdx.x * 256 + threadIdx.x;
    if (r >= NROWS) return;
    const float* x = h + (size_t)r * HDIM;
    float tot = 0.f;
    #pragma unroll
    for (int half = 0; half < 2; ++half) {
        const float* a = x + half * 128;
        float rr[8];
        #pragma unroll
        for (int jj = 0; jj < 8; ++jj) rr[jj] = mul_rn(a[jj], a[jj]);
        #pragma unroll 1
        for (int ii = 8; ii < 128; ii += 8) {
            #pragma unroll
            for (int jj = 0; jj < 8; ++jj) rr[jj] = add_rn(rr[jj], mul_rn(a[ii + jj], a[ii + jj]));
        }
        float blk = add_rn(add_rn(add_rn(rr[0], rr[1]), add_rn(rr[2], rr[3])),
                           add_rn(add_rn(rr[4], rr[5]), add_rn(rr[6], rr[7])));
        tot = (half == 0) ? blk : add_rn(tot, blk);
    }
    float den = fmaxf(sqrtf(tot), 1e-12f);
    float* o = hn + (size_t)r * HDIM;
    for (int ii = 0; ii < HDIM; ++ii) o[ii] = x[ii] / den;
}

// ======== full-row top-11 (chunked fallback, proven) ========
__global__ __launch_bounds__(256)
void topk_wave(const float* __restrict__ sim, int r0, int R,
               int* __restrict__ idx_out, float* __restrict__ wgt_out)
{
    const int wid = blockIdx.x * 4 + (threadIdx.x >> 6);
    const int lane = threadIdx.x & 63;
    if (wid >= R) return;
    const float* row = sim + (size_t)wid * NROWS;

    float av[KNN]; int ai[KNN];
    #pragma unroll
    for (int j = 0; j < KNN; ++j) { av[j] = -3.402823e38f; ai[j] = 0x7fffffff; }

    #pragma unroll 1
    for (int it = 0; it < NROWS / 256; ++it) {
        float4 v4 = *(const float4*)&row[lane * 4 + it * 256];
        float vv[4] = {v4.x, v4.y, v4.z, v4.w};
        #pragma unroll
        for (int q = 0; q < 4; ++q)
            ins11f(av, ai, vv[q], lane * 4 + it * 256 + q);
    }

    #pragma unroll 1
    for (int m = 1; m < 64; m <<= 1) {
        float bv[KNN]; int bi[KNN];
        #pragma unroll
        for (int j = 0; j < KNN; ++j) {
            bv[j] = __shfl_xor(av[j], m, 64);
            bi[j] = __shfl_xor(ai[j], m, 64);
        }
        #pragma unroll
        for (int j = 0; j < KNN; ++j)
            ins11f(av, ai, bv[j], bi[j]);
    }

    if (lane == 0) {
        double s = 0.0;
        #pragma unroll
        for (int j = 0; j < KNN; ++j) s += (double)av[j];
        double den = fmax(s, 1.0);
        int gr = r0 + wid;
        #pragma unroll
        for (int j = 0; j < KNN; ++j) {
            idx_out[(size_t)gr * KNN + j] = ai[j];
            wgt_out[(size_t)gr * KNN + j] = (float)((double)av[j] / den);
        }
    }
}

// ================= fused SDE (proven) =================
#define SROWS 16
#define SSTR  (HDIM + 4)

__device__ __forceinline__ void sde_layer(
    const float (*in)[SSTR], float (*out)[SSTR],
    const float* __restrict__ W, const float* __restrict__ bias,
    const float* __restrict__ tw, float t, int rg, int cg)
{
    __syncthreads();
    float acc[4][4];
    #pragma unroll
    for (int i = 0; i < 4; ++i)
        #pragma unroll
        for (int j = 0; j < 4; ++j) acc[i][j] = 0.f;

    #pragma unroll 1
    for (int k = 0; k < HDIM; k += 4) {
        float4 a4[4];
        #pragma unroll
        for (int i = 0; i < 4; ++i) a4[i] = *(const float4*)&in[rg * 4 + i][k];
        float4 w4[4];
        #pragma unroll
        for (int q = 0; q < 4; ++q) w4[q] = *(const float4*)&W[(size_t)(k + q) * HDIM + cg * 4];
        #pragma unroll
        for (int i = 0; i < 4; ++i) {
            float avv[4] = {a4[i].x, a4[i].y, a4[i].z, a4[i].w};
            #pragma unroll
            for (int q = 0; q < 4; ++q) {
                acc[i][0] = __builtin_fmaf(avv[q], w4[q].x, acc[i][0]);
                acc[i][1] = __builtin_fmaf(avv[q], w4[q].y, acc[i][1]);
                acc[i][2] = __builtin_fmaf(avv[q], w4[q].z, acc[i][2]);
                acc[i][3] = __builtin_fmaf(avv[q], w4[q].w, acc[i][3]);
            }
        }
    }

    float bb[4];
    #pragma unroll
    for (int j = 0; j < 4; ++j) {
        bb[j] = bias[cg * 4 + j];
        if (tw) bb[j] += t * tw[cg * 4 + j];
    }
    #pragma unroll
    for (int i = 0; i < 4; ++i)
        #pragma unroll
        for (int j = 0; j < 4; ++j)
            out[rg * 4 + i][cg * 4 + j] = tanhf(acc[i][j] + bb[j]);
}

__global__ __launch_bounds__(256)
void sde_fused(const float* __restrict__ w1, const float* __restrict__ b1,
               const float* __restrict__ w2, const float* __restrict__ b2,
               const float* __restrict__ w3, const float* __restrict__ b3,
               float* __restrict__ h)
{
    __shared__ float hs[SROWS][SSTR];
    __shared__ float bufA[SROWS][SSTR];
    __shared__ float bufB[SROWS][SSTR];
    const int tid = threadIdx.x;
    const int r0 = blockIdx.x * SROWS;
    const int rg = tid >> 6;
    const int cg = tid & 63;

    for (int i = tid; i < SROWS * HDIM; i += 256) {
        int r = i >> 8, c = i & 255;
        hs[r][c] = h[(size_t)(r0 + r) * HDIM + c];
    }

    #pragma unroll 1
    for (int s = 0; s < 10; ++s) {
        float t = 0.1f * (float)s;
        sde_layer(hs,  bufA, w1, b1, w1 + (size_t)HDIM * HDIM, t, rg, cg);
        sde_layer(bufA, bufB, w2, b2, nullptr, 0.f, rg, cg);
        sde_layer(bufB, bufA, w3, b3, nullptr, 0.f, rg, cg);
        __syncthreads();
        for (int i = tid; i < SROWS * HDIM; i += 256) {
            int r = i >> 8, c = i & 255;
            hs[r][c] += 0.1f * bufA[r][c];
        }
    }
    __syncthreads();
    for (int i = tid; i < SROWS * HDIM; i += 256) {
        int r = i >> 8, c = i & 255;
        h[(size_t)(r0 + r) * HDIM + c] = hs[r][c];
    }
}

// ================= downstream 64-tile GEMM (proven) =================
template<int EPI, bool TRANSB>
__global__ __launch_bounds__(256)
void gemm_f32(const float* __restrict__ A, int lda,
              const float* __restrict__ B, int ldb,
              const float* __restrict__ bias, const float* __restrict__ bias2, float bcoef,
              float* __restrict__ C, int ldc,
              int M, int N, int K,
              const float* __restrict__ E1, const float* __restrict__ E2, float coef)
{
    __shared__ float As[16][64];
    __shared__ float Bs[16][64];
    const int tid = threadIdx.x;
    const int tx = tid & 15, ty = tid >> 4;
    const int m0 = blockIdx.y * 64, n0 = blockIdx.x * 64;

    float acc[4][4] = {{0.f}};

    for (int k0 = 0; k0 < K; k0 += 16) {
        #pragma unroll
        for (int u = 0; u < 4; ++u) {
            int i = tid + u * 256;
            int kk = i & 15, m = i >> 4;
            int gm = m0 + m, gk = k0 + kk;
            As[kk][m] = (gm < M && gk < K) ? A[(size_t)gm * lda + gk] : 0.f;
        }
        if (!TRANSB) {
            #pragma unroll
            for (int u = 0; u < 4; ++u) {
                int i = tid + u * 256;
                int n = i & 63, kk = i >> 6;
                int gk = k0 + kk, gn = n0 + n;
                Bs[kk][n] = (gk < K && gn < N) ? B[(size_t)gk * ldb + gn] : 0.f;
            }
        } else {
            #pragma unroll
            for (int u = 0; u < 4; ++u) {
                int i = tid + u * 256;
                int kk = i & 15, n = i >> 4;
                int gk = k0 + kk, gn = n0 + n;
                Bs[kk][n] = (gk < K && gn < N) ? B[(size_t)gn * ldb + gk] : 0.f;
            }
        }
        __syncthreads();
        #pragma unroll
        for (int kk = 0; kk < 16; ++kk) {
            float4 avv = *(const float4*)&As[kk][ty * 4];
            float4 bvv = *(const float4*)&Bs[kk][tx * 4];
            float a[4] = {avv.x, avv.y, avv.z, avv.w};
            float b[4] = {bvv.x, bvv.y, bvv.z, bvv.w};
            #pragma unroll
            for (int i2 = 0; i2 < 4; ++i2)
                #pragma unroll
                for (int j = 0; j < 4; ++j)
                    acc[i2][j] += a[i2] * b[j];
        }
        __syncthreads();
    }

    #pragma unroll
    for (int i2 = 0; i2 < 4; ++i2) {
        int gm = m0 + ty * 4 + i2;
        if (gm >= M) continue;
        #pragma unroll
        for (int j = 0; j < 4; ++j) {
            int gn = n0 + tx * 4 + j;
            if (gn >= N) continue;
            float z = acc[i2][j];
            if (bias)  z += bias[gn];
            if (bias2) z += bcoef * bias2[gn];
            float r;
            if constexpr (EPI == EPI_NONE) {
                r = z;
            } else if constexpr (EPI == EPI_RELU) {
                r = fmaxf(z, 0.f);
            } else if constexpr (EPI == EPI_TANH) {
                r = tanhf(z);
            } else if constexpr (EPI == EPI_GATE) {
                float g = 1.f / (1.f + expf(-z));
                float avv = E1[(size_t)gm * ldc + gn];
                float hvv = E2[(size_t)gm * ldc + gn];
                r = fmaxf(g * avv + (1.f - g) * hvv, 0.f);
            } else {
                r = E1[(size_t)gm * ldc + gn] + tanhf(z) * coef;
            }
            C[(size_t)gm * ldc + gn] = r;
        }
    }
}

__global__ __launch_bounds__(256)
void gather_agg(const float* __restrict__ ht, const int* __restrict__ idx,
                const float* __restrict__ wgt, float* __restrict__ agg)
{
    int r = blockIdx.x, tid = threadIdx.x;
    __shared__ int   si[KNN];
    __shared__ float sw[KNN];
    if (tid < KNN) { si[tid] = idx[(size_t)r * KNN + tid]; sw[tid] = wgt[(size_t)r * KNN + tid]; }
    __syncthreads();
    float acc = 0.f;
    #pragma unroll
    for (int j = 0; j < KNN; ++j) acc += sw[j] * ht[(size_t)si[j] * HDIM + tid];
    agg[(size_t)r * HDIM + tid] = acc;
}

__global__ __launch_bounds__(256)
void te_gbias(const float* __restrict__ w1, const float* __restrict__ b1,
              const float* __restrict__ w2, const float* __restrict__ b2,
              const float* __restrict__ gw, const float* __restrict__ gb,
              float t, float* __restrict__ gbias)
{
    __shared__ float hid[16];
    __shared__ float te[256];
    int tid = threadIdx.x;
    if (tid < 16) hid[tid] = fmaxf(t * w1[tid] + b1[tid], 0.f);
    __syncthreads();
    float acc = b2[tid];
    #pragma unroll
    for (int i = 0; i < 16; ++i) acc += hid[i] * w2[i * 256 + tid];
    te[tid] = acc;
    __syncthreads();
    float g = gb[tid];
    for (int j = 0; j < 256; ++j) g += te[j] * gw[j * 256 + tid];
    gbias[tid] = g;
}

extern "C" void kernel_launch(void* const* d_in, const int* in_sizes, int n_in,
                              void* d_out, int out_size, void* d_ws, size_t ws_size,
                              hipStream_t stream)
{
    (void)in_sizes; (void)n_in; (void)out_size;
    const float* x       = (const float*)d_in[0];
    const float* enc_w1  = (const float*)d_in[1];
    const float* enc_b1  = (const float*)d_in[2];
    const float* enc_w2  = (const float*)d_in[3];
    const float* enc_b2  = (const float*)d_in[4];
    const float* bn_g    = (const float*)d_in[5];
    const float* bn_b    = (const float*)d_in[6];
    const float* bn_m    = (const float*)d_in[7];
    const float* bn_v    = (const float*)d_in[8];
    const float* tg_node_w = (const float*)d_in[9];
    const float* tg_node_b = (const float*)d_in[10];
    const float* tg_t_w1 = (const float*)d_in[11];
    const float* tg_t_b1 = (const float*)d_in[12];
    const float* tg_t_w2 = (const float*)d_in[13];
    const float* tg_t_b2 = (const float*)d_in[14];
    const float* tg_gate_w = (const float*)d_in[15];
    const float* tg_gate_b = (const float*)d_in[16];
    const float* sde_w1  = (const float*)d_in[17];
    const float* sde_b1  = (const float*)d_in[18];
    const float* sde_w2  = (const float*)d_in[19];
    const float* sde_b2  = (const float*)d_in[20];
    const float* sde_w3  = (const float*)d_in[21];
    const float* sde_b3  = (const float*)d_in[22];
    const float* dec_w1  = (const float*)d_in[23];
    const float* dec_b1  = (const float*)d_in[24];
    const float* dec_w2  = (const float*)d_in[25];
    const float* dec_b2  = (const float*)d_in[26];
    float* out = (float*)d_out;

    const size_t NH = (size_t)NROWS * HDIM;
    const size_t NK = (size_t)NROWS * KNN;
    const size_t PACKED_BYTES = (size_t)NTILES * TILE_ELEMS * 4          // 136.3 MB
                              + 2 * (size_t)NROWS * CSTR * 4;            // + 46 MB cand

    char* p = (char*)d_ws;
    float* h    = (float*)p;  p += NH * 4;
    float* hn   = (float*)p;  p += NH * 4;
    float* t1   = (float*)p;  p += NH * 4;
    float* t2   = (float*)p;  p += NH * 4;
    int*   ki   = (int*)p;    p += NK * 4;
    float* kw   = (float*)p;  p += NK * 4;
    float* bn_r   = (float*)p; p += 256 * 4;
    float* gbias  = (float*)p; p += 256 * 4;
    p += (16 - ((uintptr_t)p & 15)) & 15;
    float* simw = (float*)p;

    size_t used_bytes = (size_t)(p - (char*)d_ws);
    size_t availB = (ws_size > used_bytes) ? ws_size - used_bytes : 0;
    bool packed = (availB >= PACKED_BYTES);

    float* cv = simw + (size_t)NTILES * TILE_ELEMS;
    int*   ci = (int*)(cv + (size_t)NROWS * CSTR);

    int chunk = 128;
    if (!packed) {
        long long avail2 = (long long)availB;
        chunk = (avail2 > 0) ? (int)(avail2 / ((long long)NROWS * 4)) : 128;
        if (chunk > NROWS) chunk = NROWS;
        chunk &= ~127;
        if (chunk < 128) chunk = 128;
    }

    dim3 blk(256);
    dim3 g64(4, NROWS / 64);
    dim3 g128(2, NROWS / 128);

    bn_prep_np<<<1, 256, 0, stream>>>(bn_v, bn_r);

    // ---- np-matching MULADD chain: encoder -> norm -> sim -> top-11
    gemm_ma2<NPE_RELU, false><<<g128, blk, 0, stream>>>(
        x, 83, enc_w1, 256, enc_b1, t1, 256, NROWS, 256, 83, nullptr, nullptr, nullptr, nullptr);
    gemm_ma2<NPE_RELU_BN, false><<<g128, blk, 0, stream>>>(
        t1, 256, enc_w2, 256, enc_b2, h, 256, NROWS, 256, 256, bn_m, bn_r, bn_g, bn_b);
    rownorm_np2<<<NROWS / 256, 256, 0, stream>>>(h, hn);

    if (packed) {
        gemm_sim_sym_packed<<<NTILES, blk, 0, stream>>>(hn, simw);
        topk_direct<<<NROWS / 4, 256, 0, stream>>>(simw, cv, ci);
        topk_mirror<<<NTILES, 256, 0, stream>>>(simw, cv, ci);
        topk_merge_b<<<NROWS / 4, 256, 0, stream>>>(cv, ci, ki, kw);
    } else {
        for (int r0 = 0; r0 < NROWS; r0 += chunk) {
            int R = NROWS - r0; if (R > chunk) R = chunk;
            gemm_ma2<NPE_NONE, true><<<dim3(NROWS / 128, (R + 127) / 128), blk, 0, stream>>>(
                hn + (size_t)r0 * HDIM, HDIM, hn, HDIM, nullptr,
                simw, NROWS, R, NROWS, HDIM, nullptr, nullptr, nullptr, nullptr);
            topk_wave<<<(R + 3) / 4, 256, 0, stream>>>(simw, r0, R, ki, kw);
        }
    }

    // ---- temporal gated graph conv layers (proven 64-tile fp32)
    float tval = 0.f;
    for (int l = 0; l < 2; ++l) {
        te_gbias<<<1, 256, 0, stream>>>(
            tg_t_w1 + l * 16, tg_t_b1 + l * 16,
            tg_t_w2 + (size_t)l * 16 * 256, tg_t_b2 + l * 256,
            tg_gate_w + ((size_t)l * 512 + 256) * 256, tg_gate_b + l * 256,
            tval, gbias);
        gemm_f32<EPI_NONE, false><<<g64, blk, 0, stream>>>(
            h, 256, tg_node_w + (size_t)l * 256 * 256, 256,
            tg_node_b + l * 256, nullptr, 0.f, t1, 256, NROWS, 256, 256,
            nullptr, nullptr, 0.f);
        gather_agg<<<NROWS, 256, 0, stream>>>(t1, ki, kw, t2);
        gemm_f32<EPI_GATE, false><<<g64, blk, 0, stream>>>(
            t2, 256, tg_gate_w + (size_t)l * 512 * 256, 256,
            gbias, nullptr, 0.f, h, 256, NROWS, 256, 256,
            t2, t1, 0.f);
        tval += 0.5f;
    }

    // ---- fused SDE
    sde_fused<<<NROWS / SROWS, 256, 0, stream>>>(
        sde_w1, sde_b1, sde_w2, sde_b2, sde_w3, sde_b3, h);

    // ---- decoder
    gemm_f32<EPI_RELU, false><<<dim3(2, NROWS / 64), blk, 0, stream>>>(
        h, 256, dec_w1, 128, dec_b1, nullptr, 0.f, t1, 128, NROWS, 128, 256,
        nullptr, nullptr, 0.f);
    gemm_f32<EPI_NONE, false><<<dim3(1, NROWS / 64), blk, 0, stream>>>(
        t1, 128, dec_w2, 34, dec_b2, nullptr, 0.f, out, 34, NROWS, 34, 128,
        nullptr, nullptr, 0.f);
}

// Round 18
// 2224.778 us; speedup vs baseline: 1.1409x; 1.0532x over previous
//
#include <hip/hip_runtime.h>
#include <cmath>
#include <cstddef>

#define NROWS 8192
#define HDIM  256
#define KNN   11
#define NT    64          // 8192/128 tile bands
#define TS    128
#define TILE_ELEMS (TS*TS)
#define NTILES (NT*(NT+1)/2)

enum { EPI_NONE=0, EPI_RELU=1, EPI_TANH=3, EPI_GATE=4, EPI_SDE=5 };
enum { NPE_NONE=0, NPE_RELU=1, NPE_RELU_BN=2 };

// ---- contraction-proof single-rounding f32 ops (np ufunc semantics) ----
__device__ __forceinline__ float add_rn(float a, float b){ float d; asm("v_add_f32 %0, %1, %2":"=v"(d):"v"(a),"v"(b)); return d; }
__device__ __forceinline__ float sub_rn(float a, float b){ float d; asm("v_sub_f32 %0, %1, %2":"=v"(d):"v"(a),"v"(b)); return d; }
__device__ __forceinline__ float mul_rn(float a, float b){ float d; asm("v_mul_f32 %0, %1, %2":"=v"(d):"v"(a),"v"(b)); return d; }

__device__ __host__ __forceinline__ size_t tidx(int br, int bc)
{   // row-major upper-triangle packing, br <= bc
    return (size_t)br * NT - (size_t)br * (br - 1) / 2 + (size_t)(bc - br);
}

__device__ __forceinline__ float epi_apply(int EPI, float z, int gn,
    const float* bias, const float* bn_m, const float* bn_r,
    const float* bn_g, const float* bn_b)
{
    if (EPI == NPE_NONE) return z;
    z = add_rn(z, bias[gn]);
    z = fmaxf(z, 0.f);
    if (EPI == NPE_RELU) return z;
    z = sub_rn(z, bn_m[gn]);
    z = mul_rn(z, bn_r[gn]);
    z = mul_rn(z, bn_g[gn]);
    z = add_rn(z, bn_b[gn]);
    return z;
}

// ======== MULADD-chain GEMM: 128x128 tile, 8x8/thread, k-major LDS (proven) ========
template<int EPI, bool TRANSB>
__global__ __launch_bounds__(256)
void gemm_ma2(const float* __restrict__ A, int lda,
              const float* __restrict__ B, int ldb,
              const float* __restrict__ bias,
              float* __restrict__ C, int ldc,
              int M, int N, int K,
              const float* __restrict__ bn_m, const float* __restrict__ bn_r,
              const float* __restrict__ bn_g, const float* __restrict__ bn_b)
{
    __shared__ float As[32][132];
    __shared__ float Bs[32][132];
    const int tid = threadIdx.x;
    const int tx = tid & 15, ty = tid >> 4;
    const int m0 = blockIdx.y * 128, n0 = blockIdx.x * 128;

    float acc[8][8];
    #pragma unroll
    for (int i = 0; i < 8; ++i)
        #pragma unroll
        for (int j = 0; j < 8; ++j) acc[i][j] = 0.f;

    for (int kc = 0; kc < K; kc += 32) {
        #pragma unroll
        for (int u = 0; u < 16; ++u) {
            int idx = tid + u * 256;
            int kk = idx & 31, m = idx >> 5;
            int gm = m0 + m, gk = kc + kk;
            As[kk][m] = (gm < M && gk < K) ? A[(size_t)gm * lda + gk] : 0.f;
        }
        #pragma unroll
        for (int u = 0; u < 16; ++u) {
            int idx = tid + u * 256;
            if (TRANSB) {
                int kk = idx & 31, n = idx >> 5;
                int gn = n0 + n, gk = kc + kk;
                Bs[kk][n] = (gn < N && gk < K) ? B[(size_t)gn * ldb + gk] : 0.f;
            } else {
                int n = idx & 127, kk = idx >> 7;
                int gn = n0 + n, gk = kc + kk;
                Bs[kk][n] = (gk < K && gn < N) ? B[(size_t)gk * ldb + gn] : 0.f;
            }
        }
        __syncthreads();
        #pragma unroll
        for (int kk = 0; kk < 32; ++kk) {
            float4 a0 = *(const float4*)&As[kk][ty * 8];
            float4 a1 = *(const float4*)&As[kk][ty * 8 + 4];
            float4 b0 = *(const float4*)&Bs[kk][tx * 8];
            float4 b1 = *(const float4*)&Bs[kk][tx * 8 + 4];
            float a[8] = {a0.x,a0.y,a0.z,a0.w,a1.x,a1.y,a1.z,a1.w};
            float b[8] = {b0.x,b0.y,b0.z,b0.w,b1.x,b1.y,b1.z,b1.w};
            #pragma unroll
            for (int i = 0; i < 8; ++i)
                #pragma unroll
                for (int j = 0; j < 8; ++j)
                    acc[i][j] = add_rn(acc[i][j], mul_rn(a[i], b[j]));
        }
        __syncthreads();
    }

    #pragma unroll
    for (int i = 0; i < 8; ++i) {
        int gm = m0 + ty * 8 + i;
        if (gm >= M) continue;
        #pragma unroll
        for (int j = 0; j < 8; ++j) {
            int gn = n0 + tx * 8 + j;
            if (gn >= N) continue;
            C[(size_t)gm * ldc + gn] = epi_apply(EPI, acc[i][j], gn, bias, bn_m, bn_r, bn_g, bn_b);
        }
    }
}

// ======== sym sim GEMM -> PACKED upper tiles; 1D grid; occupancy hint ========
// __launch_bounds__(256,4): request 4 waves/EU (=4 blocks/CU for 256-thread
// blocks). VGPR cap 128; R15 build used 116 -> no spill, same arithmetic.
__global__ __launch_bounds__(256, 4)
void gemm_sim_sym_packed(const float* __restrict__ hn, float* __restrict__ P)
{
    size_t t = blockIdx.x;
    int br = 0;
    while ((size_t)(br + 1) * NT - (size_t)(br + 1) * br / 2 <= t) ++br;
    int bc = br + (int)(t - ((size_t)br * NT - (size_t)br * (br - 1) / 2));

    __shared__ float As[32][132];
    __shared__ float Bs[32][132];
    const int tid = threadIdx.x;
    const int tx = tid & 15, ty = tid >> 4;
    const int m0 = br * 128, n0 = bc * 128;

    float acc[8][8];
    #pragma unroll
    for (int i = 0; i < 8; ++i)
        #pragma unroll
        for (int j = 0; j < 8; ++j) acc[i][j] = 0.f;

    #pragma unroll 1
    for (int kc = 0; kc < HDIM; kc += 32) {
        #pragma unroll
        for (int u = 0; u < 16; ++u) {
            int idx = tid + u * 256;
            int kk = idx & 31, m = idx >> 5;
            As[kk][m] = hn[(size_t)(m0 + m) * HDIM + kc + kk];
            Bs[kk][m] = hn[(size_t)(n0 + m) * HDIM + kc + kk];
        }
        __syncthreads();
        #pragma unroll
        for (int kk = 0; kk < 32; ++kk) {
            float4 a0 = *(const float4*)&As[kk][ty * 8];
            float4 a1 = *(const float4*)&As[kk][ty * 8 + 4];
            float4 b0 = *(const float4*)&Bs[kk][tx * 8];
            float4 b1 = *(const float4*)&Bs[kk][tx * 8 + 4];
            float a[8] = {a0.x,a0.y,a0.z,a0.w,a1.x,a1.y,a1.z,a1.w};
            float b[8] = {b0.x,b0.y,b0.z,b0.w,b1.x,b1.y,b1.z,b1.w};
            #pragma unroll
            for (int i = 0; i < 8; ++i)
                #pragma unroll
                for (int j = 0; j < 8; ++j)
                    acc[i][j] = add_rn(acc[i][j], mul_rn(a[i], b[j]));
        }
        __syncthreads();
    }

    float* tile = P + t * TILE_ELEMS;
    #pragma unroll
    for (int i = 0; i < 8; ++i) {
        float* tr = tile + (size_t)(ty * 8 + i) * TS + tx * 8;
        #pragma unroll
        for (int j = 0; j < 8; ++j) tr[j] = acc[i][j];
    }
}

// ---- BN reciprocal-sqrt ----
__global__ void bn_prep_np(const float* __restrict__ v, float* __restrict__ r)
{
    int i = threadIdx.x;
    float vpe = add_rn(v[i], 1e-5f);
    r[i] = 1.0f / sqrtf(vpe);
}

// ---- numpy scalar-pairwise row L2-normalize ----
__global__ __launch_bounds__(256)
void rownorm_np2(const float* __restrict__ h, float* __restrict__ hn)
{
    int r = blockIdx.x * 256 + threadIdx.x;
    if (r >= NROWS) return;
    const float* x = h + (size_t)r * HDIM;
    float tot = 0.f;
    #pragma unroll
    for (int half = 0; half < 2; ++half) {
        const float* a = x + half * 128;
        float rr[8];
        #pragma unroll
        for (int jj = 0; jj < 8; ++jj) rr[jj] = mul_rn(a[jj], a[jj]);
        #pragma unroll 1
        for (int ii = 8; ii < 128; ii += 8) {
            #pragma unroll
            for (int jj = 0; jj < 8; ++jj) rr[jj] = add_rn(rr[jj], mul_rn(a[ii + jj], a[ii + jj]));
        }
        float blk = add_rn(add_rn(add_rn(rr[0], rr[1]), add_rn(rr[2], rr[3])),
                           add_rn(add_rn(rr[4], rr[5]), add_rn(rr[6], rr[7])));
        tot = (half == 0) ? blk : add_rn(tot, blk);
    }
    float den = fmaxf(sqrtf(tot), 1e-12f);
    float* o = hn + (size_t)r * HDIM;
    for (int ii = 0; ii < HDIM; ++ii) o[ii] = x[ii] / den;
}

// ---- guarded sorted-insert (exact: under strict >, v <= current min never enters) ----
__device__ __forceinline__ void ins11(float (&av)[KNN], int (&ai)[KNN], float v, int vi)
{
    if (v > av[KNN - 1]) {
        #pragma unroll
        for (int j = 0; j < KNN; ++j) {
            bool better = (v > av[j]);
            float tv = better ? av[j] : v;  int ti = better ? ai[j] : vi;
            av[j] = better ? v : av[j];     ai[j] = better ? vi : ai[j];
            v = tv; vi = ti;
        }
    }
}

// ======== wave-per-row top-11 over PACKED tiles; mirror via block LDS staging (R15, proven) ========
__global__ __launch_bounds__(256)
void topk_wave_sym(const float* __restrict__ P,
                   int* __restrict__ idx_out, float* __restrict__ wgt_out)
{
    __shared__ float colbuf[4][132];
    const int tid = threadIdx.x;
    const int w = tid >> 6;
    const int lane = tid & 63;
    const int wid0 = blockIdx.x * 4;
    const int wid = wid0 + w;
    const int br = wid >> 7, rr = wid & 127;
    const int rr0 = wid0 & 127;          // multiple of 4; all 4 rows in same band

    float av[KNN]; int ai[KNN];
    #pragma unroll
    for (int j = 0; j < KNN; ++j) { av[j] = -3.402823e38f; ai[j] = 0x7fffffff; }

    #pragma unroll 1
    for (int cb = 0; cb < NT; ++cb) {
        int c0 = cb * TS + lane * 2;
        if (cb >= br) {
            const float* tile = P + tidx(br, cb) * TILE_ELEMS;
            float2 v2 = *(const float2*)&tile[(size_t)rr * TS + lane * 2];
            ins11(av, ai, v2.x, c0);
            ins11(av, ai, v2.y, c0 + 1);
        } else {
            const float* tile = P + tidx(cb, br) * TILE_ELEMS;
            __syncthreads();
            if (tid < 128) {
                float4 v4 = *(const float4*)&tile[(size_t)tid * TS + rr0];
                colbuf[0][tid] = v4.x; colbuf[1][tid] = v4.y;
                colbuf[2][tid] = v4.z; colbuf[3][tid] = v4.w;
            }
            __syncthreads();
            float va = colbuf[w][lane * 2];
            float vb = colbuf[w][lane * 2 + 1];
            ins11(av, ai, va, c0);
            ins11(av, ai, vb, c0 + 1);
        }
    }

    // butterfly merge across 64 lanes; comparator (v desc, idx asc)
    #pragma unroll 1
    for (int m = 1; m < 64; m <<= 1) {
        float bv[KNN]; int bi[KNN];
        #pragma unroll
        for (int j = 0; j < KNN; ++j) {
            bv[j] = __shfl_xor(av[j], m, 64);
            bi[j] = __shfl_xor(ai[j], m, 64);
        }
        #pragma unroll
        for (int j = 0; j < KNN; ++j) {
            float v = bv[j]; int vi = bi[j];
            bool enter = (v > av[KNN - 1]) || (v == av[KNN - 1] && vi < ai[KNN - 1]);
            if (enter) {
                #pragma unroll
                for (int q = 0; q < KNN; ++q) {
                    bool better = (v > av[q]) || (v == av[q] && vi < ai[q]);
                    float tv = better ? av[q] : v;  int ti = better ? ai[q] : vi;
                    av[q] = better ? v : av[q];     ai[q] = better ? vi : ai[q];
                    v = tv; vi = ti;
                }
            }
        }
    }

    if (lane == 0) {
        double s = 0.0;
        #pragma unroll
        for (int j = 0; j < KNN; ++j) s += (double)av[j];
        double den = fmax(s, 1.0);
        #pragma unroll
        for (int j = 0; j < KNN; ++j) {
            idx_out[(size_t)wid * KNN + j] = ai[j];
            wgt_out[(size_t)wid * KNN + j] = (float)((double)av[j] / den);
        }
    }
}

// ======== full-row top-11 (chunked fallback path, proven) ========
__global__ __launch_bounds__(256)
void topk_wave(const float* __restrict__ sim, int r0, int R,
               int* __restrict__ idx_out, float* __restrict__ wgt_out)
{
    const int wid = blockIdx.x * 4 + (threadIdx.x >> 6);
    const int lane = threadIdx.x & 63;
    if (wid >= R) return;
    const float* row = sim + (size_t)wid * NROWS;

    float av[KNN]; int ai[KNN];
    #pragma unroll
    for (int j = 0; j < KNN; ++j) { av[j] = -3.402823e38f; ai[j] = 0x7fffffff; }

    #pragma unroll 1
    for (int it = 0; it < NROWS / 256; ++it) {
        float4 v4 = *(const float4*)&row[lane * 4 + it * 256];
        float vv[4] = {v4.x, v4.y, v4.z, v4.w};
        #pragma unroll
        for (int q = 0; q < 4; ++q)
            ins11(av, ai, vv[q], lane * 4 + it * 256 + q);
    }

    #pragma unroll 1
    for (int m = 1; m < 64; m <<= 1) {
        float bv[KNN]; int bi[KNN];
        #pragma unroll
        for (int j = 0; j < KNN; ++j) {
            bv[j] = __shfl_xor(av[j], m, 64);
            bi[j] = __shfl_xor(ai[j], m, 64);
        }
        #pragma unroll
        for (int j = 0; j < KNN; ++j) {
            float v = bv[j]; int vi = bi[j];
            bool enter = (v > av[KNN - 1]) || (v == av[KNN - 1] && vi < ai[KNN - 1]);
            if (enter) {
                #pragma unroll
                for (int q = 0; q < KNN; ++q) {
                    bool better = (v > av[q]) || (v == av[q] && vi < ai[q]);
                    float tv = better ? av[q] : v;  int ti = better ? ai[q] : vi;
                    av[q] = better ? v : av[q];     ai[q] = better ? vi : ai[q];
                    v = tv; vi = ti;
                }
            }
        }
    }

    if (lane == 0) {
        double s = 0.0;
        #pragma unroll
        for (int j = 0; j < KNN; ++j) s += (double)av[j];
        double den = fmax(s, 1.0);
        int gr = r0 + wid;
        #pragma unroll
        for (int j = 0; j < KNN; ++j) {
            idx_out[(size_t)gr * KNN + j] = ai[j];
            wgt_out[(size_t)gr * KNN + j] = (float)((double)av[j] / den);
        }
    }
}

// ================= fused SDE (proven) =================
#define SROWS 16
#define SSTR  (HDIM + 4)

__device__ __forceinline__ void sde_layer(
    const float (*in)[SSTR], float (*out)[SSTR],
    const float* __restrict__ W, const float* __restrict__ bias,
    const float* __restrict__ tw, float t, int rg, int cg)
{
    __syncthreads();
    float acc[4][4];
    #pragma unroll
    for (int i = 0; i < 4; ++i)
        #pragma unroll
        for (int j = 0; j < 4; ++j) acc[i][j] = 0.f;

    #pragma unroll 1
    for (int k = 0; k < HDIM; k += 4) {
        float4 a4[4];
        #pragma unroll
        for (int i = 0; i < 4; ++i) a4[i] = *(const float4*)&in[rg * 4 + i][k];
        float4 w4[4];
        #pragma unroll
        for (int q = 0; q < 4; ++q) w4[q] = *(const float4*)&W[(size_t)(k + q) * HDIM + cg * 4];
        #pragma unroll
        for (int i = 0; i < 4; ++i) {
            float avv[4] = {a4[i].x, a4[i].y, a4[i].z, a4[i].w};
            #pragma unroll
            for (int q = 0; q < 4; ++q) {
                acc[i][0] = __builtin_fmaf(avv[q], w4[q].x, acc[i][0]);
                acc[i][1] = __builtin_fmaf(avv[q], w4[q].y, acc[i][1]);
                acc[i][2] = __builtin_fmaf(avv[q], w4[q].z, acc[i][2]);
                acc[i][3] = __builtin_fmaf(avv[q], w4[q].w, acc[i][3]);
            }
        }
    }

    float bb[4];
    #pragma unroll
    for (int j = 0; j < 4; ++j) {
        bb[j] = bias[cg * 4 + j];
        if (tw) bb[j] += t * tw[cg * 4 + j];
    }
    #pragma unroll
    for (int i = 0; i < 4; ++i)
        #pragma unroll
        for (int j = 0; j < 4; ++j)
            out[rg * 4 + i][cg * 4 + j] = tanhf(acc[i][j] + bb[j]);
}

__global__ __launch_bounds__(256)
void sde_fused(const float* __restrict__ w1, const float* __restrict__ b1,
               const float* __restrict__ w2, const float* __restrict__ b2,
               const float* __restrict__ w3, const float* __restrict__ b3,
               float* __restrict__ h)
{
    __shared__ float hs[SROWS][SSTR];
    __shared__ float bufA[SROWS][SSTR];
    __shared__ float bufB[SROWS][SSTR];
    const int tid = threadIdx.x;
    const int r0 = blockIdx.x * SROWS;
    const int rg = tid >> 6;
    const int cg = tid & 63;

    for (int i = tid; i < SROWS * HDIM; i += 256) {
        int r = i >> 8, c = i & 255;
        hs[r][c] = h[(size_t)(r0 + r) * HDIM + c];
    }

    #pragma unroll 1
    for (int s = 0; s < 10; ++s) {
        float t = 0.1f * (float)s;
        sde_layer(hs,  bufA, w1, b1, w1 + (size_t)HDIM * HDIM, t, rg, cg);
        sde_layer(bufA, bufB, w2, b2, nullptr, 0.f, rg, cg);
        sde_layer(bufB, bufA, w3, b3, nullptr, 0.f, rg, cg);
        __syncthreads();
        for (int i = tid; i < SROWS * HDIM; i += 256) {
            int r = i >> 8, c = i & 255;
            hs[r][c] += 0.1f * bufA[r][c];
        }
    }
    __syncthreads();
    for (int i = tid; i < SROWS * HDIM; i += 256) {
        int r = i >> 8, c = i & 255;
        h[(size_t)(r0 + r) * HDIM + c] = hs[r][c];
    }
}

// ================= downstream 64-tile GEMM (proven) =================
template<int EPI, bool TRANSB>
__global__ __launch_bounds__(256)
void gemm_f32(const float* __restrict__ A, int lda,
              const float* __restrict__ B, int ldb,
              const float* __restrict__ bias, const float* __restrict__ bias2, float bcoef,
              float* __restrict__ C, int ldc,
              int M, int N, int K,
              const float* __restrict__ E1, const float* __restrict__ E2, float coef)
{
    __shared__ float As[16][64];
    __shared__ float Bs[16][64];
    const int tid = threadIdx.x;
    const int tx = tid & 15, ty = tid >> 4;
    const int m0 = blockIdx.y * 64, n0 = blockIdx.x * 64;

    float acc[4][4] = {{0.f}};

    for (int k0 = 0; k0 < K; k0 += 16) {
        #pragma unroll
        for (int u = 0; u < 4; ++u) {
            int i = tid + u * 256;
            int kk = i & 15, m = i >> 4;
            int gm = m0 + m, gk = k0 + kk;
            As[kk][m] = (gm < M && gk < K) ? A[(size_t)gm * lda + gk] : 0.f;
        }
        if (!TRANSB) {
            #pragma unroll
            for (int u = 0; u < 4; ++u) {
                int i = tid + u * 256;
                int n = i & 63, kk = i >> 6;
                int gk = k0 + kk, gn = n0 + n;
                Bs[kk][n] = (gk < K && gn < N) ? B[(size_t)gk * ldb + gn] : 0.f;
            }
        } else {
            #pragma unroll
            for (int u = 0; u < 4; ++u) {
                int i = tid + u * 256;
                int kk = i & 15, n = i >> 4;
                int gk = k0 + kk, gn = n0 + n;
                Bs[kk][n] = (gk < K && gn < N) ? B[(size_t)gn * ldb + gk] : 0.f;
            }
        }
        __syncthreads();
        #pragma unroll
        for (int kk = 0; kk < 16; ++kk) {
            float4 avv = *(const float4*)&As[kk][ty * 4];
            float4 bvv = *(const float4*)&Bs[kk][tx * 4];
            float a[4] = {avv.x, avv.y, avv.z, avv.w};
            float b[4] = {bvv.x, bvv.y, bvv.z, bvv.w};
            #pragma unroll
            for (int i2 = 0; i2 < 4; ++i2)
                #pragma unroll
                for (int j = 0; j < 4; ++j)
                    acc[i2][j] += a[i2] * b[j];
        }
        __syncthreads();
    }

    #pragma unroll
    for (int i2 = 0; i2 < 4; ++i2) {
        int gm = m0 + ty * 4 + i2;
        if (gm >= M) continue;
        #pragma unroll
        for (int j = 0; j < 4; ++j) {
            int gn = n0 + tx * 4 + j;
            if (gn >= N) continue;
            float z = acc[i2][j];
            if (bias)  z += bias[gn];
            if (bias2) z += bcoef * bias2[gn];
            float r;
            if constexpr (EPI == EPI_NONE) {
                r = z;
            } else if constexpr (EPI == EPI_RELU) {
                r = fmaxf(z, 0.f);
            } else if constexpr (EPI == EPI_TANH) {
                r = tanhf(z);
            } else if constexpr (EPI == EPI_GATE) {
                float g = 1.f / (1.f + expf(-z));
                float avv = E1[(size_t)gm * ldc + gn];
                float hvv = E2[(size_t)gm * ldc + gn];
                r = fmaxf(g * avv + (1.f - g) * hvv, 0.f);
            } else {
                r = E1[(size_t)gm * ldc + gn] + tanhf(z) * coef;
            }
            C[(size_t)gm * ldc + gn] = r;
        }
    }
}

__global__ __launch_bounds__(256)
void gather_agg(const float* __restrict__ ht, const int* __restrict__ idx,
                const float* __restrict__ wgt, float* __restrict__ agg)
{
    int r = blockIdx.x, tid = threadIdx.x;
    __shared__ int   si[KNN];
    __shared__ float sw[KNN];
    if (tid < KNN) { si[tid] = idx[(size_t)r * KNN + tid]; sw[tid] = wgt[(size_t)r * KNN + tid]; }
    __syncthreads();
    float acc = 0.f;
    #pragma unroll
    for (int j = 0; j < KNN; ++j) acc += sw[j] * ht[(size_t)si[j] * HDIM + tid];
    agg[(size_t)r * HDIM + tid] = acc;
}

__global__ __launch_bounds__(256)
void te_gbias(const float* __restrict__ w1, const float* __restrict__ b1,
              const float* __restrict__ w2, const float* __restrict__ b2,
              const float* __restrict__ gw, const float* __restrict__ gb,
              float t, float* __restrict__ gbias)
{
    __shared__ float hid[16];
    __shared__ float te[256];
    int tid = threadIdx.x;
    if (tid < 16) hid[tid] = fmaxf(t * w1[tid] + b1[tid], 0.f);
    __syncthreads();
    float acc = b2[tid];
    #pragma unroll
    for (int i = 0; i < 16; ++i) acc += hid[i] * w2[i * 256 + tid];
    te[tid] = acc;
    __syncthreads();
    float g = gb[tid];
    for (int j = 0; j < 256; ++j) g += te[j] * gw[j * 256 + tid];
    gbias[tid] = g;
}

extern "C" void kernel_launch(void* const* d_in, const int* in_sizes, int n_in,
                              void* d_out, int out_size, void* d_ws, size_t ws_size,
                              hipStream_t stream)
{
    (void)in_sizes; (void)n_in; (void)out_size;
    const float* x       = (const float*)d_in[0];
    const float* enc_w1  = (const float*)d_in[1];
    const float* enc_b1  = (const float*)d_in[2];
    const float* enc_w2  = (const float*)d_in[3];
    const float* enc_b2  = (const float*)d_in[4];
    const float* bn_g    = (const float*)d_in[5];
    const float* bn_b    = (const float*)d_in[6];
    const float* bn_m    = (const float*)d_in[7];
    const float* bn_v    = (const float*)d_in[8];
    const float* tg_node_w = (const float*)d_in[9];
    const float* tg_node_b = (const float*)d_in[10];
    const float* tg_t_w1 = (const float*)d_in[11];
    const float* tg_t_b1 = (const float*)d_in[12];
    const float* tg_t_w2 = (const float*)d_in[13];
    const float* tg_t_b2 = (const float*)d_in[14];
    const float* tg_gate_w = (const float*)d_in[15];
    const float* tg_gate_b = (const float*)d_in[16];
    const float* sde_w1  = (const float*)d_in[17];
    const float* sde_b1  = (const float*)d_in[18];
    const float* sde_w2  = (const float*)d_in[19];
    const float* sde_b2  = (const float*)d_in[20];
    const float* sde_w3  = (const float*)d_in[21];
    const float* sde_b3  = (const float*)d_in[22];
    const float* dec_w1  = (const float*)d_in[23];
    const float* dec_b1  = (const float*)d_in[24];
    const float* dec_w2  = (const float*)d_in[25];
    const float* dec_b2  = (const float*)d_in[26];
    float* out = (float*)d_out;

    const size_t NH = (size_t)NROWS * HDIM;
    const size_t NK = (size_t)NROWS * KNN;
    const size_t PACKED_BYTES = (size_t)NTILES * TILE_ELEMS * 4;  // 136.3 MB

    char* p = (char*)d_ws;
    float* h    = (float*)p;  p += NH * 4;
    float* hn   = (float*)p;  p += NH * 4;
    float* t1   = (float*)p;  p += NH * 4;
    float* t2   = (float*)p;  p += NH * 4;
    int*   ki   = (int*)p;    p += NK * 4;
    float* kw   = (float*)p;  p += NK * 4;
    float* bn_r   = (float*)p; p += 256 * 4;
    float* gbias  = (float*)p; p += 256 * 4;
    p += (16 - ((uintptr_t)p & 15)) & 15;
    float* simw = (float*)p;   // packed tiles OR chunked sim rows

    size_t used_bytes = (size_t)(p - (char*)d_ws);
    size_t availB = (ws_size > used_bytes) ? ws_size - used_bytes : 0;
    bool packed = (availB >= PACKED_BYTES);

    int chunk = 128;
    if (!packed) {
        long long avail2 = (long long)availB;
        chunk = (avail2 > 0) ? (int)(avail2 / ((long long)NROWS * 4)) : 128;
        if (chunk > NROWS) chunk = NROWS;
        chunk &= ~127;
        if (chunk < 128) chunk = 128;
    }

    dim3 blk(256);
    dim3 g64(4, NROWS / 64);
    dim3 g128(2, NROWS / 128);

    bn_prep_np<<<1, 256, 0, stream>>>(bn_v, bn_r);

    // ---- np-matching MULADD chain: encoder -> norm -> sim -> top-11
    gemm_ma2<NPE_RELU, false><<<g128, blk, 0, stream>>>(
        x, 83, enc_w1, 256, enc_b1, t1, 256, NROWS, 256, 83, nullptr, nullptr, nullptr, nullptr);
    gemm_ma2<NPE_RELU_BN, false><<<g128, blk, 0, stream>>>(
        t1, 256, enc_w2, 256, enc_b2, h, 256, NROWS, 256, 256, bn_m, bn_r, bn_g, bn_b);
    rownorm_np2<<<NROWS / 256, 256, 0, stream>>>(h, hn);

    if (packed) {
        gemm_sim_sym_packed<<<NTILES, blk, 0, stream>>>(hn, simw);
        topk_wave_sym<<<NROWS / 4, 256, 0, stream>>>(simw, ki, kw);
    } else {
        for (int r0 = 0; r0 < NROWS; r0 += chunk) {
            int R = NROWS - r0; if (R > chunk) R = chunk;
            gemm_ma2<NPE_NONE, true><<<dim3(NROWS / 128, (R + 127) / 128), blk, 0, stream>>>(
                hn + (size_t)r0 * HDIM, HDIM, hn, HDIM, nullptr,
                simw, NROWS, R, NROWS, HDIM, nullptr, nullptr, nullptr, nullptr);
            topk_wave<<<(R + 3) / 4, 256, 0, stream>>>(simw, r0, R, ki, kw);
        }
    }

    // ---- temporal gated graph conv layers (proven 64-tile fp32)
    float tval = 0.f;
    for (int l = 0; l < 2; ++l) {
        te_gbias<<<1, 256, 0, stream>>>(
            tg_t_w1 + l * 16, tg_t_b1 + l * 16,
            tg_t_w2 + (size_t)l * 16 * 256, tg_t_b2 + l * 256,
            tg_gate_w + ((size_t)l * 512 + 256) * 256, tg_gate_b + l * 256,
            tval, gbias);
        gemm_f32<EPI_NONE, false><<<g64, blk, 0, stream>>>(
            h, 256, tg_node_w + (size_t)l * 256 * 256, 256,
            tg_node_b + l * 256, nullptr, 0.f, t1, 256, NROWS, 256, 256,
            nullptr, nullptr, 0.f);
        gather_agg<<<NROWS, 256, 0, stream>>>(t1, ki, kw, t2);
        gemm_f32<EPI_GATE, false><<<g64, blk, 0, stream>>>(
            t2, 256, tg_gate_w + (size_t)l * 512 * 256, 256,
            gbias, nullptr, 0.f, h, 256, NROWS, 256, 256,
            t2, t1, 0.f);
        tval += 0.5f;
    }

    // ---- fused SDE
    sde_fused<<<NROWS / SROWS, 256, 0, stream>>>(
        sde_w1, sde_b1, sde_w2, sde_b2, sde_w3, sde_b3, h);

    // ---- decoder
    gemm_f32<EPI_RELU, false><<<dim3(2, NROWS / 64), blk, 0, stream>>>(
        h, 256, dec_w1, 128, dec_b1, nullptr, 0.f, t1, 128, NROWS, 128, 256,
        nullptr, nullptr, 0.f);
    gemm_f32<EPI_NONE, false><<<dim3(1, NROWS / 64), blk, 0, stream>>>(
        t1, 128, dec_w2, 34, dec_b2, nullptr, 0.f, out, 34, NROWS, 34, 128,
        nullptr, nullptr, 0.f);
}

// Round 19
// 1880.289 us; speedup vs baseline: 1.3499x; 1.1832x over previous
//
#include <hip/hip_runtime.h>
#include <cmath>
#include <cstddef>

#define NROWS 8192
#define HDIM  256
#define KNN   11
#define NT    64          // 8192/128 tile bands
#define TS    128
#define TILE_ELEMS (TS*TS)
#define NTILES (NT*(NT+1)/2)

enum { EPI_NONE=0, EPI_RELU=1, EPI_TANH=3, EPI_GATE=4, EPI_SDE=5 };
enum { NPE_NONE=0, NPE_RELU=1, NPE_RELU_BN=2 };

typedef __attribute__((ext_vector_type(2))) float v2f;

// ---- contraction-proof single-rounding f32 ops (np ufunc semantics) ----
__device__ __forceinline__ float add_rn(float a, float b){ float d; asm("v_add_f32 %0, %1, %2":"=v"(d):"v"(a),"v"(b)); return d; }
__device__ __forceinline__ float sub_rn(float a, float b){ float d; asm("v_sub_f32 %0, %1, %2":"=v"(d):"v"(a),"v"(b)); return d; }
__device__ __forceinline__ float mul_rn(float a, float b){ float d; asm("v_mul_f32 %0, %1, %2":"=v"(d):"v"(a),"v"(b)); return d; }

// ---- packed dual-f32 MULADD, per-element rounding identical to v_mul/v_add.
// acc.lo += a2.lo * b; acc.hi += a2.hi * b  where b = b2.lo (LO) or b2.hi (HI).
__device__ __forceinline__ void pk_mac_lo(v2f &acc, v2f a2, v2f b2){
    v2f p;
    asm("v_pk_mul_f32 %0, %1, %2 op_sel:[0,0] op_sel_hi:[1,0]" : "=v"(p) : "v"(a2), "v"(b2));
    asm("v_pk_add_f32 %0, %1, %2" : "=v"(acc) : "v"(acc), "v"(p));
}
__device__ __forceinline__ void pk_mac_hi(v2f &acc, v2f a2, v2f b2){
    v2f p;
    asm("v_pk_mul_f32 %0, %1, %2 op_sel:[0,1] op_sel_hi:[1,1]" : "=v"(p) : "v"(a2), "v"(b2));
    asm("v_pk_add_f32 %0, %1, %2" : "=v"(acc) : "v"(acc), "v"(p));
}

__device__ __host__ __forceinline__ size_t tidx(int br, int bc)
{   // row-major upper-triangle packing, br <= bc
    return (size_t)br * NT - (size_t)br * (br - 1) / 2 + (size_t)(bc - br);
}

__device__ __forceinline__ float epi_apply(int EPI, float z, int gn,
    const float* bias, const float* bn_m, const float* bn_r,
    const float* bn_g, const float* bn_b)
{
    if (EPI == NPE_NONE) return z;
    z = add_rn(z, bias[gn]);
    z = fmaxf(z, 0.f);
    if (EPI == NPE_RELU) return z;
    z = sub_rn(z, bn_m[gn]);
    z = mul_rn(z, bn_r[gn]);
    z = mul_rn(z, bn_g[gn]);
    z = add_rn(z, bn_b[gn]);
    return z;
}

// ======== MULADD-chain GEMM: 128x128 tile, 8x8/thread, k-major LDS (proven) ========
template<int EPI, bool TRANSB>
__global__ __launch_bounds__(256)
void gemm_ma2(const float* __restrict__ A, int lda,
              const float* __restrict__ B, int ldb,
              const float* __restrict__ bias,
              float* __restrict__ C, int ldc,
              int M, int N, int K,
              const float* __restrict__ bn_m, const float* __restrict__ bn_r,
              const float* __restrict__ bn_g, const float* __restrict__ bn_b)
{
    __shared__ float As[32][132];
    __shared__ float Bs[32][132];
    const int tid = threadIdx.x;
    const int tx = tid & 15, ty = tid >> 4;
    const int m0 = blockIdx.y * 128, n0 = blockIdx.x * 128;

    float acc[8][8];
    #pragma unroll
    for (int i = 0; i < 8; ++i)
        #pragma unroll
        for (int j = 0; j < 8; ++j) acc[i][j] = 0.f;

    for (int kc = 0; kc < K; kc += 32) {
        #pragma unroll
        for (int u = 0; u < 16; ++u) {
            int idx = tid + u * 256;
            int kk = idx & 31, m = idx >> 5;
            int gm = m0 + m, gk = kc + kk;
            As[kk][m] = (gm < M && gk < K) ? A[(size_t)gm * lda + gk] : 0.f;
        }
        #pragma unroll
        for (int u = 0; u < 16; ++u) {
            int idx = tid + u * 256;
            if (TRANSB) {
                int kk = idx & 31, n = idx >> 5;
                int gn = n0 + n, gk = kc + kk;
                Bs[kk][n] = (gn < N && gk < K) ? B[(size_t)gn * ldb + gk] : 0.f;
            } else {
                int n = idx & 127, kk = idx >> 7;
                int gn = n0 + n, gk = kc + kk;
                Bs[kk][n] = (gk < K && gn < N) ? B[(size_t)gk * ldb + gn] : 0.f;
            }
        }
        __syncthreads();
        #pragma unroll
        for (int kk = 0; kk < 32; ++kk) {
            float4 a0 = *(const float4*)&As[kk][ty * 8];
            float4 a1 = *(const float4*)&As[kk][ty * 8 + 4];
            float4 b0 = *(const float4*)&Bs[kk][tx * 8];
            float4 b1 = *(const float4*)&Bs[kk][tx * 8 + 4];
            float a[8] = {a0.x,a0.y,a0.z,a0.w,a1.x,a1.y,a1.z,a1.w};
            float b[8] = {b0.x,b0.y,b0.z,b0.w,b1.x,b1.y,b1.z,b1.w};
            #pragma unroll
            for (int i = 0; i < 8; ++i)
                #pragma unroll
                for (int j = 0; j < 8; ++j)
                    acc[i][j] = add_rn(acc[i][j], mul_rn(a[i], b[j]));
        }
        __syncthreads();
    }

    #pragma unroll
    for (int i = 0; i < 8; ++i) {
        int gm = m0 + ty * 8 + i;
        if (gm >= M) continue;
        #pragma unroll
        for (int j = 0; j < 8; ++j) {
            int gn = n0 + tx * 8 + j;
            if (gn >= N) continue;
            C[(size_t)gm * ldc + gn] = epi_apply(EPI, acc[i][j], gn, bias, bn_m, bn_r, bn_g, bn_b);
        }
    }
}

// ======== sym sim GEMM -> PACKED upper tiles; packed-f32 MULADD inner loop ========
// acc2[ip][j] = (acc[2ip][j], acc[2ip+1][j]); per-element rounding and k-order
// identical to the scalar MULADD chain (v_pk = two independent IEEE f32 ops).
__global__ __launch_bounds__(256)
void gemm_sim_sym_packed(const float* __restrict__ hn, float* __restrict__ P)
{
    size_t t = blockIdx.x;
    int br = 0;
    while ((size_t)(br + 1) * NT - (size_t)(br + 1) * br / 2 <= t) ++br;
    int bc = br + (int)(t - ((size_t)br * NT - (size_t)br * (br - 1) / 2));

    __shared__ float As[32][132];
    __shared__ float Bs[32][132];
    const int tid = threadIdx.x;
    const int tx = tid & 15, ty = tid >> 4;
    const int m0 = br * 128, n0 = bc * 128;

    v2f acc2[4][8];
    #pragma unroll
    for (int ip = 0; ip < 4; ++ip)
        #pragma unroll
        for (int j = 0; j < 8; ++j) { acc2[ip][j].x = 0.f; acc2[ip][j].y = 0.f; }

    #pragma unroll 1
    for (int kc = 0; kc < HDIM; kc += 32) {
        #pragma unroll
        for (int u = 0; u < 16; ++u) {
            int idx = tid + u * 256;
            int kk = idx & 31, m = idx >> 5;
            As[kk][m] = hn[(size_t)(m0 + m) * HDIM + kc + kk];
            Bs[kk][m] = hn[(size_t)(n0 + m) * HDIM + kc + kk];
        }
        __syncthreads();
        #pragma unroll
        for (int kk = 0; kk < 32; ++kk) {
            float4 a0 = *(const float4*)&As[kk][ty * 8];
            float4 a1 = *(const float4*)&As[kk][ty * 8 + 4];
            float4 b0 = *(const float4*)&Bs[kk][tx * 8];
            float4 b1 = *(const float4*)&Bs[kk][tx * 8 + 4];
            v2f a2[4], b2[4];
            a2[0].x = a0.x; a2[0].y = a0.y;  a2[1].x = a0.z; a2[1].y = a0.w;
            a2[2].x = a1.x; a2[2].y = a1.y;  a2[3].x = a1.z; a2[3].y = a1.w;
            b2[0].x = b0.x; b2[0].y = b0.y;  b2[1].x = b0.z; b2[1].y = b0.w;
            b2[2].x = b1.x; b2[2].y = b1.y;  b2[3].x = b1.z; b2[3].y = b1.w;
            #pragma unroll
            for (int ip = 0; ip < 4; ++ip)
                #pragma unroll
                for (int jp = 0; jp < 4; ++jp) {
                    pk_mac_lo(acc2[ip][2 * jp],     a2[ip], b2[jp]);
                    pk_mac_hi(acc2[ip][2 * jp + 1], a2[ip], b2[jp]);
                }
        }
        __syncthreads();
    }

    float* tile = P + t * TILE_ELEMS;
    #pragma unroll
    for (int ip = 0; ip < 4; ++ip) {
        float* tr0 = tile + (size_t)(ty * 8 + 2 * ip) * TS + tx * 8;
        float* tr1 = tile + (size_t)(ty * 8 + 2 * ip + 1) * TS + tx * 8;
        #pragma unroll
        for (int j = 0; j < 8; ++j) {
            tr0[j] = acc2[ip][j].x;
            tr1[j] = acc2[ip][j].y;
        }
    }
}

// ---- BN reciprocal-sqrt ----
__global__ void bn_prep_np(const float* __restrict__ v, float* __restrict__ r)
{
    int i = threadIdx.x;
    float vpe = add_rn(v[i], 1e-5f);
    r[i] = 1.0f / sqrtf(vpe);
}

// ---- numpy scalar-pairwise row L2-normalize ----
__global__ __launch_bounds__(256)
void rownorm_np2(const float* __restrict__ h, float* __restrict__ hn)
{
    int r = blockIdx.x * 256 + threadIdx.x;
    if (r >= NROWS) return;
    const float* x = h + (size_t)r * HDIM;
    float tot = 0.f;
    #pragma unroll
    for (int half = 0; half < 2; ++half) {
        const float* a = x + half * 128;
        float rr[8];
        #pragma unroll
        for (int jj = 0; jj < 8; ++jj) rr[jj] = mul_rn(a[jj], a[jj]);
        #pragma unroll 1
        for (int ii = 8; ii < 128; ii += 8) {
            #pragma unroll
            for (int jj = 0; jj < 8; ++jj) rr[jj] = add_rn(rr[jj], mul_rn(a[ii + jj], a[ii + jj]));
        }
        float blk = add_rn(add_rn(add_rn(rr[0], rr[1]), add_rn(rr[2], rr[3])),
                           add_rn(add_rn(rr[4], rr[5]), add_rn(rr[6], rr[7])));
        tot = (half == 0) ? blk : add_rn(tot, blk);
    }
    float den = fmaxf(sqrtf(tot), 1e-12f);
    float* o = hn + (size_t)r * HDIM;
    for (int ii = 0; ii < HDIM; ++ii) o[ii] = x[ii] / den;
}

// ---- guarded sorted-insert (exact: under strict >, v <= current min never enters) ----
__device__ __forceinline__ void ins11(float (&av)[KNN], int (&ai)[KNN], float v, int vi)
{
    if (v > av[KNN - 1]) {
        #pragma unroll
        for (int j = 0; j < KNN; ++j) {
            bool better = (v > av[j]);
            float tv = better ? av[j] : v;  int ti = better ? ai[j] : vi;
            av[j] = better ? v : av[j];     ai[j] = better ? vi : ai[j];
            v = tv; vi = ti;
        }
    }
}

// ======== wave-per-row top-11 over PACKED tiles; mirror via block LDS staging (R15, proven) ========
__global__ __launch_bounds__(256)
void topk_wave_sym(const float* __restrict__ P,
                   int* __restrict__ idx_out, float* __restrict__ wgt_out)
{
    __shared__ float colbuf[4][132];
    const int tid = threadIdx.x;
    const int w = tid >> 6;
    const int lane = tid & 63;
    const int wid0 = blockIdx.x * 4;
    const int wid = wid0 + w;
    const int br = wid >> 7, rr = wid & 127;
    const int rr0 = wid0 & 127;          // multiple of 4; all 4 rows in same band

    float av[KNN]; int ai[KNN];
    #pragma unroll
    for (int j = 0; j < KNN; ++j) { av[j] = -3.402823e38f; ai[j] = 0x7fffffff; }

    #pragma unroll 1
    for (int cb = 0; cb < NT; ++cb) {
        int c0 = cb * TS + lane * 2;
        if (cb >= br) {
            const float* tile = P + tidx(br, cb) * TILE_ELEMS;
            float2 v2 = *(const float2*)&tile[(size_t)rr * TS + lane * 2];
            ins11(av, ai, v2.x, c0);
            ins11(av, ai, v2.y, c0 + 1);
        } else {
            const float* tile = P + tidx(cb, br) * TILE_ELEMS;
            __syncthreads();
            if (tid < 128) {
                float4 v4 = *(const float4*)&tile[(size_t)tid * TS + rr0];
                colbuf[0][tid] = v4.x; colbuf[1][tid] = v4.y;
                colbuf[2][tid] = v4.z; colbuf[3][tid] = v4.w;
            }
            __syncthreads();
            float va = colbuf[w][lane * 2];
            float vb = colbuf[w][lane * 2 + 1];
            ins11(av, ai, va, c0);
            ins11(av, ai, vb, c0 + 1);
        }
    }

    // butterfly merge across 64 lanes; comparator (v desc, idx asc)
    #pragma unroll 1
    for (int m = 1; m < 64; m <<= 1) {
        float bv[KNN]; int bi[KNN];
        #pragma unroll
        for (int j = 0; j < KNN; ++j) {
            bv[j] = __shfl_xor(av[j], m, 64);
            bi[j] = __shfl_xor(ai[j], m, 64);
        }
        #pragma unroll
        for (int j = 0; j < KNN; ++j) {
            float v = bv[j]; int vi = bi[j];
            bool enter = (v > av[KNN - 1]) || (v == av[KNN - 1] && vi < ai[KNN - 1]);
            if (enter) {
                #pragma unroll
                for (int q = 0; q < KNN; ++q) {
                    bool better = (v > av[q]) || (v == av[q] && vi < ai[q]);
                    float tv = better ? av[q] : v;  int ti = better ? ai[q] : vi;
                    av[q] = better ? v : av[q];     ai[q] = better ? vi : ai[q];
                    v = tv; vi = ti;
                }
            }
        }
    }

    if (lane == 0) {
        double s = 0.0;
        #pragma unroll
        for (int j = 0; j < KNN; ++j) s += (double)av[j];
        double den = fmax(s, 1.0);
        #pragma unroll
        for (int j = 0; j < KNN; ++j) {
            idx_out[(size_t)wid * KNN + j] = ai[j];
            wgt_out[(size_t)wid * KNN + j] = (float)((double)av[j] / den);
        }
    }
}

// ======== full-row top-11 (chunked fallback path, proven) ========
__global__ __launch_bounds__(256)
void topk_wave(const float* __restrict__ sim, int r0, int R,
               int* __restrict__ idx_out, float* __restrict__ wgt_out)
{
    const int wid = blockIdx.x * 4 + (threadIdx.x >> 6);
    const int lane = threadIdx.x & 63;
    if (wid >= R) return;
    const float* row = sim + (size_t)wid * NROWS;

    float av[KNN]; int ai[KNN];
    #pragma unroll
    for (int j = 0; j < KNN; ++j) { av[j] = -3.402823e38f; ai[j] = 0x7fffffff; }

    #pragma unroll 1
    for (int it = 0; it < NROWS / 256; ++it) {
        float4 v4 = *(const float4*)&row[lane * 4 + it * 256];
        float vv[4] = {v4.x, v4.y, v4.z, v4.w};
        #pragma unroll
        for (int q = 0; q < 4; ++q)
            ins11(av, ai, vv[q], lane * 4 + it * 256 + q);
    }

    #pragma unroll 1
    for (int m = 1; m < 64; m <<= 1) {
        float bv[KNN]; int bi[KNN];
        #pragma unroll
        for (int j = 0; j < KNN; ++j) {
            bv[j] = __shfl_xor(av[j], m, 64);
            bi[j] = __shfl_xor(ai[j], m, 64);
        }
        #pragma unroll
        for (int j = 0; j < KNN; ++j) {
            float v = bv[j]; int vi = bi[j];
            bool enter = (v > av[KNN - 1]) || (v == av[KNN - 1] && vi < ai[KNN - 1]);
            if (enter) {
                #pragma unroll
                for (int q = 0; q < KNN; ++q) {
                    bool better = (v > av[q]) || (v == av[q] && vi < ai[q]);
                    float tv = better ? av[q] : v;  int ti = better ? ai[q] : vi;
                    av[q] = better ? v : av[q];     ai[q] = better ? vi : ai[q];
                    v = tv; vi = ti;
                }
            }
        }
    }

    if (lane == 0) {
        double s = 0.0;
        #pragma unroll
        for (int j = 0; j < KNN; ++j) s += (double)av[j];
        double den = fmax(s, 1.0);
        int gr = r0 + wid;
        #pragma unroll
        for (int j = 0; j < KNN; ++j) {
            idx_out[(size_t)gr * KNN + j] = ai[j];
            wgt_out[(size_t)gr * KNN + j] = (float)((double)av[j] / den);
        }
    }
}

// ================= fused SDE (proven) =================
#define SROWS 16
#define SSTR  (HDIM + 4)

__device__ __forceinline__ void sde_layer(
    const float (*in)[SSTR], float (*out)[SSTR],
    const float* __restrict__ W, const float* __restrict__ bias,
    const float* __restrict__ tw, float t, int rg, int cg)
{
    __syncthreads();
    float acc[4][4];
    #pragma unroll
    for (int i = 0; i < 4; ++i)
        #pragma unroll
        for (int j = 0; j < 4; ++j) acc[i][j] = 0.f;

    #pragma unroll 1
    for (int k = 0; k < HDIM; k += 4) {
        float4 a4[4];
        #pragma unroll
        for (int i = 0; i < 4; ++i) a4[i] = *(const float4*)&in[rg * 4 + i][k];
        float4 w4[4];
        #pragma unroll
        for (int q = 0; q < 4; ++q) w4[q] = *(const float4*)&W[(size_t)(k + q) * HDIM + cg * 4];
        #pragma unroll
        for (int i = 0; i < 4; ++i) {
            float avv[4] = {a4[i].x, a4[i].y, a4[i].z, a4[i].w};
            #pragma unroll
            for (int q = 0; q < 4; ++q) {
                acc[i][0] = __builtin_fmaf(avv[q], w4[q].x, acc[i][0]);
                acc[i][1] = __builtin_fmaf(avv[q], w4[q].y, acc[i][1]);
                acc[i][2] = __builtin_fmaf(avv[q], w4[q].z, acc[i][2]);
                acc[i][3] = __builtin_fmaf(avv[q], w4[q].w, acc[i][3]);
            }
        }
    }

    float bb[4];
    #pragma unroll
    for (int j = 0; j < 4; ++j) {
        bb[j] = bias[cg * 4 + j];
        if (tw) bb[j] += t * tw[cg * 4 + j];
    }
    #pragma unroll
    for (int i = 0; i < 4; ++i)
        #pragma unroll
        for (int j = 0; j < 4; ++j)
            out[rg * 4 + i][cg * 4 + j] = tanhf(acc[i][j] + bb[j]);
}

__global__ __launch_bounds__(256)
void sde_fused(const float* __restrict__ w1, const float* __restrict__ b1,
               const float* __restrict__ w2, const float* __restrict__ b2,
               const float* __restrict__ w3, const float* __restrict__ b3,
               float* __restrict__ h)
{
    __shared__ float hs[SROWS][SSTR];
    __shared__ float bufA[SROWS][SSTR];
    __shared__ float bufB[SROWS][SSTR];
    const int tid = threadIdx.x;
    const int r0 = blockIdx.x * SROWS;
    const int rg = tid >> 6;
    const int cg = tid & 63;

    for (int i = tid; i < SROWS * HDIM; i += 256) {
        int r = i >> 8, c = i & 255;
        hs[r][c] = h[(size_t)(r0 + r) * HDIM + c];
    }

    #pragma unroll 1
    for (int s = 0; s < 10; ++s) {
        float t = 0.1f * (float)s;
        sde_layer(hs,  bufA, w1, b1, w1 + (size_t)HDIM * HDIM, t, rg, cg);
        sde_layer(bufA, bufB, w2, b2, nullptr, 0.f, rg, cg);
        sde_layer(bufB, bufA, w3, b3, nullptr, 0.f, rg, cg);
        __syncthreads();
        for (int i = tid; i < SROWS * HDIM; i += 256) {
            int r = i >> 8, c = i & 255;
            hs[r][c] += 0.1f * bufA[r][c];
        }
    }
    __syncthreads();
    for (int i = tid; i < SROWS * HDIM; i += 256) {
        int r = i >> 8, c = i & 255;
        h[(size_t)(r0 + r) * HDIM + c] = hs[r][c];
    }
}

// ================= downstream 64-tile GEMM (proven) =================
template<int EPI, bool TRANSB>
__global__ __launch_bounds__(256)
void gemm_f32(const float* __restrict__ A, int lda,
              const float* __restrict__ B, int ldb,
              const float* __restrict__ bias, const float* __restrict__ bias2, float bcoef,
              float* __restrict__ C, int ldc,
              int M, int N, int K,
              const float* __restrict__ E1, const float* __restrict__ E2, float coef)
{
    __shared__ float As[16][64];
    __shared__ float Bs[16][64];
    const int tid = threadIdx.x;
    const int tx = tid & 15, ty = tid >> 4;
    const int m0 = blockIdx.y * 64, n0 = blockIdx.x * 64;

    float acc[4][4] = {{0.f}};

    for (int k0 = 0; k0 < K; k0 += 16) {
        #pragma unroll
        for (int u = 0; u < 4; ++u) {
            int i = tid + u * 256;
            int kk = i & 15, m = i >> 4;
            int gm = m0 + m, gk = k0 + kk;
            As[kk][m] = (gm < M && gk < K) ? A[(size_t)gm * lda + gk] : 0.f;
        }
        if (!TRANSB) {
            #pragma unroll
            for (int u = 0; u < 4; ++u) {
                int i = tid + u * 256;
                int n = i & 63, kk = i >> 6;
                int gk = k0 + kk, gn = n0 + n;
                Bs[kk][n] = (gk < K && gn < N) ? B[(size_t)gk * ldb + gn] : 0.f;
            }
        } else {
            #pragma unroll
            for (int u = 0; u < 4; ++u) {
                int i = tid + u * 256;
                int kk = i & 15, n = i >> 4;
                int gk = k0 + kk, gn = n0 + n;
                Bs[kk][n] = (gk < K && gn < N) ? B[(size_t)gn * ldb + gk] : 0.f;
            }
        }
        __syncthreads();
        #pragma unroll
        for (int kk = 0; kk < 16; ++kk) {
            float4 avv = *(const float4*)&As[kk][ty * 4];
            float4 bvv = *(const float4*)&Bs[kk][tx * 4];
            float a[4] = {avv.x, avv.y, avv.z, avv.w};
            float b[4] = {bvv.x, bvv.y, bvv.z, bvv.w};
            #pragma unroll
            for (int i2 = 0; i2 < 4; ++i2)
                #pragma unroll
                for (int j = 0; j < 4; ++j)
                    acc[i2][j] += a[i2] * b[j];
        }
        __syncthreads();
    }

    #pragma unroll
    for (int i2 = 0; i2 < 4; ++i2) {
        int gm = m0 + ty * 4 + i2;
        if (gm >= M) continue;
        #pragma unroll
        for (int j = 0; j < 4; ++j) {
            int gn = n0 + tx * 4 + j;
            if (gn >= N) continue;
            float z = acc[i2][j];
            if (bias)  z += bias[gn];
            if (bias2) z += bcoef * bias2[gn];
            float r;
            if constexpr (EPI == EPI_NONE) {
                r = z;
            } else if constexpr (EPI == EPI_RELU) {
                r = fmaxf(z, 0.f);
            } else if constexpr (EPI == EPI_TANH) {
                r = tanhf(z);
            } else if constexpr (EPI == EPI_GATE) {
                float g = 1.f / (1.f + expf(-z));
                float avv = E1[(size_t)gm * ldc + gn];
                float hvv = E2[(size_t)gm * ldc + gn];
                r = fmaxf(g * avv + (1.f - g) * hvv, 0.f);
            } else {
                r = E1[(size_t)gm * ldc + gn] + tanhf(z) * coef;
            }
            C[(size_t)gm * ldc + gn] = r;
        }
    }
}

__global__ __launch_bounds__(256)
void gather_agg(const float* __restrict__ ht, const int* __restrict__ idx,
                const float* __restrict__ wgt, float* __restrict__ agg)
{
    int r = blockIdx.x, tid = threadIdx.x;
    __shared__ int   si[KNN];
    __shared__ float sw[KNN];
    if (tid < KNN) { si[tid] = idx[(size_t)r * KNN + tid]; sw[tid] = wgt[(size_t)r * KNN + tid]; }
    __syncthreads();
    float acc = 0.f;
    #pragma unroll
    for (int j = 0; j < KNN; ++j) acc += sw[j] * ht[(size_t)si[j] * HDIM + tid];
    agg[(size_t)r * HDIM + tid] = acc;
}

__global__ __launch_bounds__(256)
void te_gbias(const float* __restrict__ w1, const float* __restrict__ b1,
              const float* __restrict__ w2, const float* __restrict__ b2,
              const float* __restrict__ gw, const float* __restrict__ gb,
              float t, float* __restrict__ gbias)
{
    __shared__ float hid[16];
    __shared__ float te[256];
    int tid = threadIdx.x;
    if (tid < 16) hid[tid] = fmaxf(t * w1[tid] + b1[tid], 0.f);
    __syncthreads();
    float acc = b2[tid];
    #pragma unroll
    for (int i = 0; i < 16; ++i) acc += hid[i] * w2[i * 256 + tid];
    te[tid] = acc;
    __syncthreads();
    float g = gb[tid];
    for (int j = 0; j < 256; ++j) g += te[j] * gw[j * 256 + tid];
    gbias[tid] = g;
}

extern "C" void kernel_launch(void* const* d_in, const int* in_sizes, int n_in,
                              void* d_out, int out_size, void* d_ws, size_t ws_size,
                              hipStream_t stream)
{
    (void)in_sizes; (void)n_in; (void)out_size;
    const float* x       = (const float*)d_in[0];
    const float* enc_w1  = (const float*)d_in[1];
    const float* enc_b1  = (const float*)d_in[2];
    const float* enc_w2  = (const float*)d_in[3];
    const float* enc_b2  = (const float*)d_in[4];
    const float* bn_g    = (const float*)d_in[5];
    const float* bn_b    = (const float*)d_in[6];
    const float* bn_m    = (const float*)d_in[7];
    const float* bn_v    = (const float*)d_in[8];
    const float* tg_node_w = (const float*)d_in[9];
    const float* tg_node_b = (const float*)d_in[10];
    const float* tg_t_w1 = (const float*)d_in[11];
    const float* tg_t_b1 = (const float*)d_in[12];
    const float* tg_t_w2 = (const float*)d_in[13];
    const float* tg_t_b2 = (const float*)d_in[14];
    const float* tg_gate_w = (const float*)d_in[15];
    const float* tg_gate_b = (const float*)d_in[16];
    const float* sde_w1  = (const float*)d_in[17];
    const float* sde_b1  = (const float*)d_in[18];
    const float* sde_w2  = (const float*)d_in[19];
    const float* sde_b2  = (const float*)d_in[20];
    const float* sde_w3  = (const float*)d_in[21];
    const float* sde_b3  = (const float*)d_in[22];
    const float* dec_w1  = (const float*)d_in[23];
    const float* dec_b1  = (const float*)d_in[24];
    const float* dec_w2  = (const float*)d_in[25];
    const float* dec_b2  = (const float*)d_in[26];
    float* out = (float*)d_out;

    const size_t NH = (size_t)NROWS * HDIM;
    const size_t NK = (size_t)NROWS * KNN;
    const size_t PACKED_BYTES = (size_t)NTILES * TILE_ELEMS * 4;  // 136.3 MB

    char* p = (char*)d_ws;
    float* h    = (float*)p;  p += NH * 4;
    float* hn   = (float*)p;  p += NH * 4;
    float* t1   = (float*)p;  p += NH * 4;
    float* t2   = (float*)p;  p += NH * 4;
    int*   ki   = (int*)p;    p += NK * 4;
    float* kw   = (float*)p;  p += NK * 4;
    float* bn_r   = (float*)p; p += 256 * 4;
    float* gbias  = (float*)p; p += 256 * 4;
    p += (16 - ((uintptr_t)p & 15)) & 15;
    float* simw = (float*)p;   // packed tiles OR chunked sim rows

    size_t used_bytes = (size_t)(p - (char*)d_ws);
    size_t availB = (ws_size > used_bytes) ? ws_size - used_bytes : 0;
    bool packed = (availB >= PACKED_BYTES);

    int chunk = 128;
    if (!packed) {
        long long avail2 = (long long)availB;
        chunk = (avail2 > 0) ? (int)(avail2 / ((long long)NROWS * 4)) : 128;
        if (chunk > NROWS) chunk = NROWS;
        chunk &= ~127;
        if (chunk < 128) chunk = 128;
    }

    dim3 blk(256);
    dim3 g64(4, NROWS / 64);
    dim3 g128(2, NROWS / 128);

    bn_prep_np<<<1, 256, 0, stream>>>(bn_v, bn_r);

    // ---- np-matching MULADD chain: encoder -> norm -> sim -> top-11
    gemm_ma2<NPE_RELU, false><<<g128, blk, 0, stream>>>(
        x, 83, enc_w1, 256, enc_b1, t1, 256, NROWS, 256, 83, nullptr, nullptr, nullptr, nullptr);
    gemm_ma2<NPE_RELU_BN, false><<<g128, blk, 0, stream>>>(
        t1, 256, enc_w2, 256, enc_b2, h, 256, NROWS, 256, 256, bn_m, bn_r, bn_g, bn_b);
    rownorm_np2<<<NROWS / 256, 256, 0, stream>>>(h, hn);

    if (packed) {
        gemm_sim_sym_packed<<<NTILES, blk, 0, stream>>>(hn, simw);
        topk_wave_sym<<<NROWS / 4, 256, 0, stream>>>(simw, ki, kw);
    } else {
        for (int r0 = 0; r0 < NROWS; r0 += chunk) {
            int R = NROWS - r0; if (R > chunk) R = chunk;
            gemm_ma2<NPE_NONE, true><<<dim3(NROWS / 128, (R + 127) / 128), blk, 0, stream>>>(
                hn + (size_t)r0 * HDIM, HDIM, hn, HDIM, nullptr,
                simw, NROWS, R, NROWS, HDIM, nullptr, nullptr, nullptr, nullptr);
            topk_wave<<<(R + 3) / 4, 256, 0, stream>>>(simw, r0, R, ki, kw);
        }
    }

    // ---- temporal gated graph conv layers (proven 64-tile fp32)
    float tval = 0.f;
    for (int l = 0; l < 2; ++l) {
        te_gbias<<<1, 256, 0, stream>>>(
            tg_t_w1 + l * 16, tg_t_b1 + l * 16,
            tg_t_w2 + (size_t)l * 16 * 256, tg_t_b2 + l * 256,
            tg_gate_w + ((size_t)l * 512 + 256) * 256, tg_gate_b + l * 256,
            tval, gbias);
        gemm_f32<EPI_NONE, false><<<g64, blk, 0, stream>>>(
            h, 256, tg_node_w + (size_t)l * 256 * 256, 256,
            tg_node_b + l * 256, nullptr, 0.f, t1, 256, NROWS, 256, 256,
            nullptr, nullptr, 0.f);
        gather_agg<<<NROWS, 256, 0, stream>>>(t1, ki, kw, t2);
        gemm_f32<EPI_GATE, false><<<g64, blk, 0, stream>>>(
            t2, 256, tg_gate_w + (size_t)l * 512 * 256, 256,
            gbias, nullptr, 0.f, h, 256, NROWS, 256, 256,
            t2, t1, 0.f);
        tval += 0.5f;
    }

    // ---- fused SDE
    sde_fused<<<NROWS / SROWS, 256, 0, stream>>>(
        sde_w1, sde_b1, sde_w2, sde_b2, sde_w3, sde_b3, h);

    // ---- decoder
    gemm_f32<EPI_RELU, false><<<dim3(2, NROWS / 64), blk, 0, stream>>>(
        h, 256, dec_w1, 128, dec_b1, nullptr, 0.f, t1, 128, NROWS, 128, 256,
        nullptr, nullptr, 0.f);
    gemm_f32<EPI_NONE, false><<<dim3(1, NROWS / 64), blk, 0, stream>>>(
        t1, 128, dec_w2, 34, dec_b2, nullptr, 0.f, out, 34, NROWS, 34, 128,
        nullptr, nullptr, 0.f);
}